// Round 12
// baseline (789.362 us; speedup 1.0000x reference)
//
#include <hip/hip_runtime.h>
#include <math.h>

#define NN 50000
#define EE 800000
#define BBG 256
#define HHC 128
#define SEG_CAP 224  // LDS x-cache rows per graph
#define ESC 512      // per-graph e-cache entries in LDS
#define NBIN 196     // coarse bins of 256 nodes
#define NBLK 196     // blocks in K1/K3 (4096 edges each)

typedef _Float16 half2 __attribute__((ext_vector_type(2)));

__device__ __forceinline__ float4 aff4(float4 v, float4 sc, float4 sh) {
  v.x = fmaxf(fmaf(v.x, sc.x, sh.x), 0.f);
  v.y = fmaxf(fmaf(v.y, sc.y, sh.y), 0.f);
  v.z = fmaxf(fmaf(v.z, sc.z, sh.z), 0.f);
  v.w = fmaxf(fmaf(v.w, sc.w, sh.w), 0.f);
  return v;
}
__device__ __forceinline__ void add4(float4& a, float4 b) {
  a.x += b.x; a.y += b.y; a.z += b.z; a.w += b.w;
}
// scalar 32-bit bitcast only — guaranteed register-level (no alloca)
__device__ __forceinline__ half2 h2(float f) { return __builtin_bit_cast(half2, f); }

// ---------------- merged prep: zero | gptr | coarse hist | weight repack ----------------
// LSTM weights -> fp16, gate-interleaved col op=4j+g, k-pair layout:
// dst = (k>>1)*1024 + op*2 + (k&1)   (rows of 1024 halves per k-pair)
__global__ __launch_bounds__(256) void prep_all_kernel(
    const int* __restrict__ batch,
    const int* __restrict__ ei,
    const float* __restrict__ W0, const float* __restrict__ W1,
    const float* __restrict__ W2, const float* __restrict__ W3,
    const float* __restrict__ Wih0, const float* __restrict__ Whh0,
    const float* __restrict__ WihR, const float* __restrict__ WhhR,
    const float* __restrict__ b0, const float* __restrict__ bR,
    float* __restrict__ stats, int* __restrict__ gptr, int* __restrict__ partial,
    float* __restrict__ ginWT, _Float16* __restrict__ WT0h,
    _Float16* __restrict__ WTRh, float* __restrict__ bc0, float* __restrict__ bcR) {
  __shared__ int hist[NBIN];
  int blk = blockIdx.x, tid = threadIdx.x;
  if (blk == 0) {
    ((float4*)stats)[tid] = make_float4(0.f, 0.f, 0.f, 0.f);  // 1024 floats
    return;
  }
  if (blk <= 196) {  // gptr boundaries
    int i = (blk - 1) * 256 + tid;
    if (i >= NN) return;
    int b = batch[i];
    int prev = (i == 0) ? -1 : batch[i - 1];
    for (int g = prev + 1; g <= b; ++g) gptr[g] = i;
    if (i == NN - 1) {
      for (int g = b + 1; g <= BBG; ++g) gptr[g] = NN;
    }
    return;
  }
  if (blk <= 392) {  // coarse hist
    int b = blk - 197;
    if (tid < NBIN) hist[tid] = 0;
    __syncthreads();
    const int4* dst4 = (const int4*)(ei + EE);
#pragma unroll
    for (int c = 0; c < 4; ++c) {
      int idx = b * 1024 + c * 256 + tid;
      if (idx < EE / 4) {
        int4 d = dst4[idx];
        atomicAdd(&hist[d.x >> 8], 1);
        atomicAdd(&hist[d.y >> 8], 1);
        atomicAdd(&hist[d.z >> 8], 1);
        atomicAdd(&hist[d.w >> 8], 1);
      }
    }
    __syncthreads();
    if (tid < NBIN) partial[tid * NBLK + b] = hist[tid];
    return;
  }
  // weight prep
  int idx = (blk - 393) * 256 + tid;  // [0, 657408)
  if (idx < 65536) {
    int m = idx >> 14;
    int r = idx & 16383;
    int k = r >> 7, o = r & 127;
    const float* W = (m == 0) ? W0 : (m == 1) ? W1 : (m == 2) ? W2 : W3;
    ginWT[idx] = W[o * 128 + k];
  } else if (idx < 262144) {
    int t = idx - 65536;
    int k = t >> 9, op = t & 511;
    int j = op >> 2, g = op & 3;
    int row = g * 128 + j;
    float v = (k < 256) ? Wih0[row * 256 + k] : Whh0[row * 128 + (k - 256)];
    WT0h[(k >> 1) * 1024 + op * 2 + (k & 1)] = (_Float16)v;
  } else if (idx < 655360) {
    int t = idx - 262144;
    int l = t >> 17;
    int rem = t & 131071;
    int k = rem >> 9, op = rem & 511;
    int j = op >> 2, g = op & 3;
    int row = g * 128 + j;
    float v = (k < 128) ? WihR[((size_t)l * 512 + row) * 128 + k]
                        : WhhR[((size_t)l * 512 + row) * 128 + (k - 128)];
    WTRh[(size_t)l * 131072 + (k >> 1) * 1024 + op * 2 + (k & 1)] = (_Float16)v;
  } else {
    int t = idx - 655360;
    if (t < 512) {
      bc0[t] = b0[(t & 3) * 128 + (t >> 2)];
    } else {
      int u = t - 512;
      int l = u >> 9, op = u & 511;
      bcR[u] = bR[l * 512 + (op & 3) * 128 + (op >> 2)];
    }
  }
}

// ---- atomic-free CSR build (two-level counting sort) ----

__global__ void scan_partials_kernel(const int* __restrict__ partial,
                                     int* __restrict__ block_base, int* __restrict__ total) {
  __shared__ int buf[256];
  int bin = blockIdx.x, tid = threadIdx.x;
  int v = (tid < NBLK) ? partial[bin * NBLK + tid] : 0;
  buf[tid] = v;
  __syncthreads();
  for (int off = 1; off < 256; off <<= 1) {
    int t = (tid >= off) ? buf[tid - off] : 0;
    __syncthreads();
    buf[tid] += t;
    __syncthreads();
  }
  if (tid < NBLK) block_base[bin * NBLK + tid] = buf[tid] - v;
  if (tid == 255) total[bin] = buf[255];
}

__global__ void scan_totals_kernel(const int* __restrict__ total, int* __restrict__ coarse_base) {
  __shared__ int buf[256];
  int tid = threadIdx.x;
  int v = (tid < NBIN) ? total[tid] : 0;
  buf[tid] = v;
  __syncthreads();
  for (int off = 1; off < 256; off <<= 1) {
    int t = (tid >= off) ? buf[tid - off] : 0;
    __syncthreads();
    buf[tid] += t;
    __syncthreads();
  }
  if (tid < NBIN) coarse_base[tid] = buf[tid] - v;
  if (tid == 255) coarse_base[NBIN] = buf[255];
}

__global__ __launch_bounds__(256) void bucket_scatter_kernel(const int* __restrict__ ei,
                                                             const int* __restrict__ coarse_base,
                                                             const int* __restrict__ block_base,
                                                             int* __restrict__ packed) {
  __shared__ int cursor[NBIN];
  int tid = threadIdx.x, b = blockIdx.x;
  if (tid < NBIN) cursor[tid] = coarse_base[tid] + block_base[tid * NBLK + b];
  __syncthreads();
  const int4* src4 = (const int4*)ei;
  const int4* dst4 = (const int4*)(ei + EE);
#pragma unroll
  for (int c = 0; c < 4; ++c) {
    int idx = b * 1024 + c * 256 + tid;
    if (idx < EE / 4) {
      int4 s = src4[idx];
      int4 d = dst4[idx];
      int p;
      p = atomicAdd(&cursor[d.x >> 8], 1); packed[p] = (s.x << 8) | (d.x & 255);
      p = atomicAdd(&cursor[d.y >> 8], 1); packed[p] = (s.y << 8) | (d.y & 255);
      p = atomicAdd(&cursor[d.z >> 8], 1); packed[p] = (s.z << 8) | (d.z & 255);
      p = atomicAdd(&cursor[d.w >> 8], 1); packed[p] = (s.w << 8) | (d.w & 255);
    }
  }
}

__global__ __launch_bounds__(256) void csr_finalize_kernel(const int* __restrict__ packed,
                                                           const int* __restrict__ coarse_base,
                                                           int* __restrict__ row_start,
                                                           int* __restrict__ csr) {
  __shared__ int fh[256];
  __shared__ int fb[256];
  int bin = blockIdx.x, tid = threadIdx.x;
  int e0 = coarse_base[bin], e1 = coarse_base[bin + 1];
  fh[tid] = 0;
  __syncthreads();
  for (int e = e0 + tid; e < e1; e += 256) atomicAdd(&fh[packed[e] & 255], 1);
  __syncthreads();
  int v = fh[tid];
  fb[tid] = v;
  __syncthreads();
  for (int off = 1; off < 256; off <<= 1) {
    int t = (tid >= off) ? fb[tid - off] : 0;
    __syncthreads();
    fb[tid] += t;
    __syncthreads();
  }
  int excl = fb[tid] - v;
  int node = bin * 256 + tid;
  if (node < NN) row_start[node] = e0 + excl;
  if (bin == NBIN - 1 && tid == 0) row_start[NN] = EE;
  __syncthreads();
  fb[tid] = excl;  // cursor
  __syncthreads();
  for (int e = e0 + tid; e < e1; e += 256) {
    int p = packed[e];
    int pos = atomicAdd(&fb[p & 255], 1);
    csr[e0 + pos] = p >> 8;
  }
}

// ---------------- GIN ----------------

// one wave per node; each 32-lane half loads a full 512B row as float4.
template <bool AFF>
__global__ __launch_bounds__(256) void gin_agg_kernel(
    const float* __restrict__ xin, const int* __restrict__ row_start,
    const int* __restrict__ csr,
    const float* __restrict__ stats, const float* __restrict__ gamma,
    const float* __restrict__ beta, float* __restrict__ outp) {
  __shared__ float sc_s[128], sh_s[128];
  if (AFF) {
    int t = threadIdx.x;
    if (t < 128) {
      const float invN = 1.0f / (float)NN;
      float mm = stats[t] * invN;
      float vv = stats[128 + t] * invN - mm * mm;
      float rs = rsqrtf(vv + 1e-5f);
      float sc = gamma[t] * rs;
      sc_s[t] = sc;
      sh_s[t] = beta[t] - mm * sc;
    }
    __syncthreads();
  }
  int node = blockIdx.x * 4 + (threadIdx.x >> 6);  // exact: 12500*4 = 50000
  int lane = threadIdx.x & 63;
  int half = lane >> 5, ln = lane & 31;
  const float4* x4 = (const float4*)xin;
  float4 sc4 = make_float4(0.f, 0.f, 0.f, 0.f), sh4 = sc4;
  if (AFF) {
    sc4 = *(const float4*)&sc_s[4 * ln];
    sh4 = *(const float4*)&sh_s[4 * ln];
  }
  int s0 = row_start[node], s1 = row_start[node + 1];
  float4 self = x4[(size_t)node * 32 + ln];
  if (AFF) self = aff4(self, sc4, sh4);
  float4 c0 = make_float4(0.f, 0.f, 0.f, 0.f), c1 = c0, c2 = c0, c3 = c0;
  int cnt = s1 - s0;
  int mainEnd = s0 + (cnt & ~15);
  for (int j = s0; j < mainEnd; j += 16) {
    int i0 = csr[j + half + 0];
    int i1 = csr[j + half + 2];
    int i2 = csr[j + half + 4];
    int i3 = csr[j + half + 6];
    int i4 = csr[j + half + 8];
    int i5 = csr[j + half + 10];
    int i6 = csr[j + half + 12];
    int i7 = csr[j + half + 14];
    float4 v0 = x4[(size_t)i0 * 32 + ln];
    float4 v1 = x4[(size_t)i1 * 32 + ln];
    float4 v2 = x4[(size_t)i2 * 32 + ln];
    float4 v3 = x4[(size_t)i3 * 32 + ln];
    float4 v4 = x4[(size_t)i4 * 32 + ln];
    float4 v5 = x4[(size_t)i5 * 32 + ln];
    float4 v6 = x4[(size_t)i6 * 32 + ln];
    float4 v7 = x4[(size_t)i7 * 32 + ln];
    if (AFF) {
      v0 = aff4(v0, sc4, sh4); v1 = aff4(v1, sc4, sh4);
      v2 = aff4(v2, sc4, sh4); v3 = aff4(v3, sc4, sh4);
      v4 = aff4(v4, sc4, sh4); v5 = aff4(v5, sc4, sh4);
      v6 = aff4(v6, sc4, sh4); v7 = aff4(v7, sc4, sh4);
    }
    add4(c0, v0); add4(c1, v1); add4(c2, v2); add4(c3, v3);
    add4(c0, v4); add4(c1, v5); add4(c2, v6); add4(c3, v7);
  }
  for (int j = mainEnd + half; j < s1; j += 2) {
    int i = csr[j];
    float4 v = x4[(size_t)i * 32 + ln];
    if (AFF) v = aff4(v, sc4, sh4);
    add4(c0, v);
  }
  float4 t;
  t.x = (c0.x + c1.x) + (c2.x + c3.x);
  t.y = (c0.y + c1.y) + (c2.y + c3.y);
  t.z = (c0.z + c1.z) + (c2.z + c3.z);
  t.w = (c0.w + c1.w) + (c2.w + c3.w);
  t.x += __shfl_xor(t.x, 32);
  t.y += __shfl_xor(t.y, 32);
  t.z += __shfl_xor(t.z, 32);
  t.w += __shfl_xor(t.w, 32);
  t.x += self.x; t.y += self.y; t.z += self.z; t.w += self.w;
  if (half == 0) ((float4*)outp)[(size_t)node * 32 + ln] = t;
}

// C = f(A) @ W^T + b, f = optional fused BN(stats)+relu; per-channel stats atomics.
template <bool BN>
__global__ __launch_bounds__(256) void gemm_gin_kernel(
    const float* __restrict__ A, const float* __restrict__ WT,
    const float* __restrict__ bias,
    const float* __restrict__ stats, const float* __restrict__ gamma,
    const float* __restrict__ beta,
    float* __restrict__ C,
    float* __restrict__ ssum, float* __restrict__ ssq, int M) {
  __shared__ float As[64][132];
  __shared__ float Wt[128][68];
  __shared__ float bsc[128], bsh[128];
  int tid = threadIdx.x;
  if (BN) {
    if (tid < 128) {
      const float invN = 1.0f / (float)NN;
      float mm = stats[tid] * invN;
      float vv = stats[128 + tid] * invN - mm * mm;
      float rs = rsqrtf(vv + 1e-5f);
      float sc = gamma[tid] * rs;
      bsc[tid] = sc;
      bsh[tid] = beta[tid] - mm * sc;
    }
    __syncthreads();
  }
  int tx = tid & 15, ty = tid >> 4;
  int bx = blockIdx.x & 1, by = blockIdx.x >> 1;
  int row0 = by * 64, c0 = bx * 64;
#pragma unroll
  for (int i = 0; i < 8; ++i) {
    int slot = tid + i * 256;
    int r = slot >> 5, k4 = (slot & 31) << 2;
    float4 v = make_float4(0.f, 0.f, 0.f, 0.f);
    if (row0 + r < M) v = *(const float4*)(A + (size_t)(row0 + r) * 128 + k4);
    if (BN) {
      v.x = fmaxf(fmaf(v.x, bsc[k4 + 0], bsh[k4 + 0]), 0.f);
      v.y = fmaxf(fmaf(v.y, bsc[k4 + 1], bsh[k4 + 1]), 0.f);
      v.z = fmaxf(fmaf(v.z, bsc[k4 + 2], bsh[k4 + 2]), 0.f);
      v.w = fmaxf(fmaf(v.w, bsc[k4 + 3], bsh[k4 + 3]), 0.f);
    }
    *(float4*)&As[r][k4] = v;
  }
#pragma unroll
  for (int i = 0; i < 8; ++i) {
    int slot = tid + i * 256;
    int k = slot >> 4, c4 = (slot & 15) << 2;
    *(float4*)&Wt[k][c4] = *(const float4*)(WT + (size_t)k * 128 + c0 + c4);
  }
  __syncthreads();
  float acc[4][4];
#pragma unroll
  for (int i = 0; i < 4; ++i)
#pragma unroll
    for (int j = 0; j < 4; ++j) acc[i][j] = 0.f;
#pragma unroll 4
  for (int kk = 0; kk < 128; kk += 4) {
    float4 w0 = *(const float4*)&Wt[kk + 0][tx << 2];
    float4 w1 = *(const float4*)&Wt[kk + 1][tx << 2];
    float4 w2 = *(const float4*)&Wt[kk + 2][tx << 2];
    float4 w3 = *(const float4*)&Wt[kk + 3][tx << 2];
#pragma unroll
    for (int i = 0; i < 4; ++i) {
      float4 a = *(const float4*)&As[(ty << 2) + i][kk];
      acc[i][0] += a.x * w0.x + a.y * w1.x + a.z * w2.x + a.w * w3.x;
      acc[i][1] += a.x * w0.y + a.y * w1.y + a.z * w2.y + a.w * w3.y;
      acc[i][2] += a.x * w0.z + a.y * w1.z + a.z * w2.z + a.w * w3.z;
      acc[i][3] += a.x * w0.w + a.y * w1.w + a.z * w2.w + a.w * w3.w;
    }
  }
  __syncthreads();
  float b0v = bias[c0 + (tx << 2) + 0];
  float b1v = bias[c0 + (tx << 2) + 1];
  float b2v = bias[c0 + (tx << 2) + 2];
  float b3v = bias[c0 + (tx << 2) + 3];
  float psum[4] = {0.f, 0.f, 0.f, 0.f}, psq[4] = {0.f, 0.f, 0.f, 0.f};
#pragma unroll
  for (int i = 0; i < 4; ++i) {
    int r = row0 + (ty << 2) + i;
    if (r < M) {
      float4 v;
      v.x = acc[i][0] + b0v; v.y = acc[i][1] + b1v;
      v.z = acc[i][2] + b2v; v.w = acc[i][3] + b3v;
      *(float4*)(C + (size_t)r * 128 + c0 + (tx << 2)) = v;
      psum[0] += v.x; psum[1] += v.y; psum[2] += v.z; psum[3] += v.w;
      psq[0] += v.x * v.x; psq[1] += v.y * v.y; psq[2] += v.z * v.z; psq[3] += v.w * v.w;
    }
  }
  float* red = &As[0][0];
#pragma unroll
  for (int j = 0; j < 4; ++j) {
    red[ty * 68 + (tx << 2) + j] = psum[j];
    red[1088 + ty * 68 + (tx << 2) + j] = psq[j];
  }
  __syncthreads();
  if (tid < 64) {
    float s = 0.f, sq = 0.f;
#pragma unroll
    for (int t = 0; t < 16; ++t) { s += red[t * 68 + tid]; sq += red[1088 + t * 68 + tid]; }
    atomicAdd(&ssum[c0 + tid], s);
    atomicAdd(&ssq[c0 + tid], sq);
  }
}

// ---------------- fused Set2Set v7: fdot2 via float4 weight loads ----------------
// Weights in k-pair layout [K/2][512][2] fp16: a float4 load's 32-bit lanes ARE
// half2(k,k+1) for 4 consecutive cols — only scalar bitcasts needed (no alloca).
// __launch_bounds__(1024,4): LDS caps us at 1 block/CU = 4 waves/EU anyway,
// so raise the VGPR cap to 128 and avoid the 64-reg spill cliff.
__global__ void __launch_bounds__(1024, 4) set2set_kernel(
    const float* __restrict__ x, const int* __restrict__ gptr,
    const float* __restrict__ stats, const float* __restrict__ gamma,
    const float* __restrict__ beta,
    const _Float16* __restrict__ WT0h, const _Float16* __restrict__ WTRh,
    const float* __restrict__ bc0, const float* __restrict__ bcR,
    float* __restrict__ ebuf,
    const float* __restrict__ linW, const float* __restrict__ linb,
    float* __restrict__ out) {
  __shared__ float xs[SEG_CAP * 128];        // 114688 B
  __shared__ float wpart[8 * 528];           // 16896 B (skewed; aliased as rpart)
  __shared__ float gates[512];
  __shared__ __align__(16) _Float16 inp_h[384];
  __shared__ float hcs[4][128];
  __shared__ float ccs[4][128];
  __shared__ float qst[256];
  __shared__ float es[ESC];                  // 2 KB
  __shared__ float bsc[128], bsh[128];
  __shared__ float wred[16];
  __shared__ float smax_s, ssum_s;
  __shared__ float fred[2][4];

  int g = blockIdx.x, tid = threadIdx.x;
  int w16 = tid >> 6, lane = tid & 63;

  // init
  if (tid < 128) {
    const float invN = 1.0f / (float)NN;
    float mm = stats[tid] * invN;
    float vv = stats[128 + tid] * invN - mm * mm;
    float rs = rsqrtf(vv + 1e-5f);
    float sc = gamma[tid] * rs;
    bsc[tid] = sc;
    bsh[tid] = beta[tid] - mm * sc;
#pragma unroll
    for (int l = 0; l < 4; ++l) { hcs[l][tid] = 0.f; ccs[l][tid] = 0.f; }
  }
  if (tid < 256) qst[tid] = 0.f;
  __syncthreads();

  int s0 = gptr[g], s1 = gptr[g + 1];
  int seg = s1 - s0;
  int ncache = seg < SEG_CAP ? seg : SEG_CAP;
  const float2* x2 = (const float2*)x;
  float sc0 = bsc[2 * lane], sc1 = bsc[2 * lane + 1];
  float sh0 = bsh[2 * lane], sh1 = bsh[2 * lane + 1];
  // stage segment into LDS once (BN4-transformed)
  for (int n = w16; n < ncache; n += 16) {
    float2 v = x2[(size_t)(s0 + n) * 64 + lane];
    xs[n * 128 + 2 * lane] = fmaxf(fmaf(v.x, sc0, sh0), 0.f);
    xs[n * 128 + 2 * lane + 1] = fmaxf(fmaf(v.y, sc1, sh1), 0.f);
  }
  __syncthreads();

  int s_ = tid >> 7, cg = tid & 127;  // matvec: K2-slice (8), col-group (4 cols)
  int pbase = s_ * 528 + 4 * cg + (cg >> 3);
  const float* inpf = (const float*)inp_h;  // 32-bit view: one word = half2(k,k+1)

  for (int step = 0; step < 4; ++step) {
    // ---- 4 stacked LSTM cells ----
    for (int cell = 0; cell < 4; ++cell) {
      const float* WTf; const float* bias; int K2;
      if (cell == 0) {
        WTf = (const float*)WT0h; bias = bc0; K2 = 192;
        if (tid < 192) {
          int e0 = 2 * tid, e1 = 2 * tid + 1;
          float f0 = (e0 < 256) ? qst[e0] : hcs[0][e0 - 256];
          float f1 = (e1 < 256) ? qst[e1] : hcs[0][e1 - 256];
          inp_h[e0] = (_Float16)f0;
          inp_h[e1] = (_Float16)f1;
        }
      } else {
        WTf = (const float*)(WTRh + (size_t)(cell - 1) * 131072);
        bias = bcR + (cell - 1) * 512; K2 = 128;
        if (tid < 128) {
          int e0 = 2 * tid, e1 = 2 * tid + 1;
          float f0 = (e0 < 128) ? hcs[cell - 1][e0] : hcs[cell][e0 - 128];
          float f1 = (e1 < 128) ? hcs[cell - 1][e1] : hcs[cell][e1 - 128];
          inp_h[e0] = (_Float16)f0;
          inp_h[e1] = (_Float16)f1;
        }
      }
      __syncthreads();
      int kper = K2 >> 3;                // 24 or 16 k-pairs per slice
      int se = (s_ + g) & 7;             // rotate slice start per block
      int k0 = se * kper;
      const float* wp = WTf + 4 * cg;    // float view: row stride = 512 floats
      float a0 = 0.f, a1 = 0.f, a2 = 0.f, a3 = 0.f;
      for (int k2 = k0; k2 < k0 + kper; k2 += 4) {
        float4 f0 = *(const float4*)(wp + (size_t)(k2 + 0) * 512);
        float4 f1 = *(const float4*)(wp + (size_t)(k2 + 1) * 512);
        float4 f2 = *(const float4*)(wp + (size_t)(k2 + 2) * 512);
        float4 f3 = *(const float4*)(wp + (size_t)(k2 + 3) * 512);
        half2 q0 = h2(inpf[k2 + 0]);
        half2 q1 = h2(inpf[k2 + 1]);
        half2 q2 = h2(inpf[k2 + 2]);
        half2 q3 = h2(inpf[k2 + 3]);
        a0 = __builtin_amdgcn_fdot2(h2(f0.x), q0, a0, false);
        a1 = __builtin_amdgcn_fdot2(h2(f0.y), q0, a1, false);
        a2 = __builtin_amdgcn_fdot2(h2(f0.z), q0, a2, false);
        a3 = __builtin_amdgcn_fdot2(h2(f0.w), q0, a3, false);
        a0 = __builtin_amdgcn_fdot2(h2(f1.x), q1, a0, false);
        a1 = __builtin_amdgcn_fdot2(h2(f1.y), q1, a1, false);
        a2 = __builtin_amdgcn_fdot2(h2(f1.z), q1, a2, false);
        a3 = __builtin_amdgcn_fdot2(h2(f1.w), q1, a3, false);
        a0 = __builtin_amdgcn_fdot2(h2(f2.x), q2, a0, false);
        a1 = __builtin_amdgcn_fdot2(h2(f2.y), q2, a1, false);
        a2 = __builtin_amdgcn_fdot2(h2(f2.z), q2, a2, false);
        a3 = __builtin_amdgcn_fdot2(h2(f2.w), q2, a3, false);
        a0 = __builtin_amdgcn_fdot2(h2(f3.x), q3, a0, false);
        a1 = __builtin_amdgcn_fdot2(h2(f3.y), q3, a1, false);
        a2 = __builtin_amdgcn_fdot2(h2(f3.z), q3, a2, false);
        a3 = __builtin_amdgcn_fdot2(h2(f3.w), q3, a3, false);
      }
      wpart[pbase + 0] = a0;
      wpart[pbase + 1] = a1;
      wpart[pbase + 2] = a2;
      wpart[pbase + 3] = a3;
      __syncthreads();
      if (tid < 512) {
        int addr = tid + (tid >> 5);
        float acc = bias[tid];
#pragma unroll
        for (int s = 0; s < 8; ++s) acc += wpart[s * 528 + addr];
        gates[tid] = acc;
      }
      __syncthreads();
      if (tid < 128) {
        int j = tid;
        float gi = gates[4 * j + 0];
        float gf = gates[4 * j + 1];
        float gc = gates[4 * j + 2];
        float go = gates[4 * j + 3];
        float cp = ccs[cell][j];
        float si = 1.f / (1.f + expf(-gi));
        float sf = 1.f / (1.f + expf(-gf));
        float so = 1.f / (1.f + expf(-go));
        float cn = sf * cp + si * tanhf(gc);
        ccs[cell][j] = cn;
        hcs[cell][j] = so * tanhf(cn);
      }
      __syncthreads();
    }
    // ---- attention, q = new h[3]; x from LDS cache ----
    float* rpart = wpart;  // alias: time-disjoint with matvec (16*128 <= 8*528)
    float qx = hcs[3][2 * lane], qy = hcs[3][2 * lane + 1];
    // pass 1: e + max
    float wmax = -3.0e38f;
    for (int n = w16; n < seg; n += 16) {
      float vx, vy;
      if (n < ncache) {
        vx = xs[n * 128 + 2 * lane];
        vy = xs[n * 128 + 2 * lane + 1];
      } else {
        float2 v = x2[(size_t)(s0 + n) * 64 + lane];
        vx = fmaxf(fmaf(v.x, sc0, sh0), 0.f);
        vy = fmaxf(fmaf(v.y, sc1, sh1), 0.f);
      }
      float e = vx * qx + vy * qy;
#pragma unroll
      for (int sh = 32; sh; sh >>= 1) e += __shfl_xor(e, sh);
      if (lane == 0) { if (n < ESC) es[n] = e; else ebuf[s0 + n] = e; }
      wmax = fmaxf(wmax, e);
    }
    if (lane == 0) wred[w16] = wmax;
    __syncthreads();
    if (tid == 0) {
      float m = wred[0];
#pragma unroll
      for (int t = 1; t < 16; ++t) m = fmaxf(m, wred[t]);
      smax_s = m;
    }
    __syncthreads();
    float m = smax_s;
    // pass 2: sum exp
    float loc = 0.f;
    for (int n = tid; n < seg; n += 1024) {
      float e = (n < ESC) ? es[n] : ebuf[s0 + n];
      loc += expf(e - m);
    }
#pragma unroll
    for (int sh = 32; sh; sh >>= 1) loc += __shfl_xor(loc, sh);
    __syncthreads();
    if (lane == 0) wred[w16] = loc;
    __syncthreads();
    if (tid == 0) {
      float s = 0.f;
#pragma unroll
      for (int t = 0; t < 16; ++t) s += wred[t];
      ssum_s = s;
    }
    __syncthreads();
    float inv = 1.0f / ssum_s;
    // pass 3: r = sum a*x
    float rx = 0.f, ry = 0.f;
    for (int n = w16; n < seg; n += 16) {
      float e = (n < ESC) ? es[n] : ebuf[s0 + n];
      float coef = expf(e - m) * inv;
      float vx, vy;
      if (n < ncache) {
        vx = xs[n * 128 + 2 * lane];
        vy = xs[n * 128 + 2 * lane + 1];
      } else {
        float2 v = x2[(size_t)(s0 + n) * 64 + lane];
        vx = fmaxf(fmaf(v.x, sc0, sh0), 0.f);
        vy = fmaxf(fmaf(v.y, sc1, sh1), 0.f);
      }
      rx += coef * vx; ry += coef * vy;
    }
    rpart[w16 * 128 + 2 * lane] = rx;
    rpart[w16 * 128 + 2 * lane + 1] = ry;
    __syncthreads();
    if (tid < 128) {
      float r = 0.f;
#pragma unroll
      for (int t = 0; t < 16; ++t) r += rpart[t * 128 + tid];
      qst[tid] = hcs[3][tid];
      qst[128 + tid] = r;
    }
    __syncthreads();
  }
  // ---- final linear ----
  if (tid < 256) {
    float val = qst[tid];
    float p0 = val * linW[tid];
    float p1 = val * linW[256 + tid];
#pragma unroll
    for (int sh = 32; sh; sh >>= 1) { p0 += __shfl_xor(p0, sh); p1 += __shfl_xor(p1, sh); }
    if (lane == 0) { fred[0][w16] = p0; fred[1][w16] = p1; }
  }
  __syncthreads();
  if (tid == 0) {
    out[2 * g + 0] = fred[0][0] + fred[0][1] + fred[0][2] + fred[0][3] + linb[0];
    out[2 * g + 1] = fred[1][0] + fred[1][1] + fred[1][2] + fred[1][3] + linb[1];
  }
}

// ---------------- launch ----------------

extern "C" void kernel_launch(void* const* d_in, const int* in_sizes, int n_in,
                              void* d_out, int out_size, void* d_ws, size_t ws_size,
                              hipStream_t stream) {
  const float* x = (const float*)d_in[0];
  const int* ei = (const int*)d_in[1];
  const int* batch = (const int*)d_in[2];
  const float* gW[4]  = {(const float*)d_in[3],  (const float*)d_in[7],
                         (const float*)d_in[11], (const float*)d_in[15]};
  const float* gb[4]  = {(const float*)d_in[4],  (const float*)d_in[8],
                         (const float*)d_in[12], (const float*)d_in[16]};
  const float* gga[4] = {(const float*)d_in[5],  (const float*)d_in[9],
                         (const float*)d_in[13], (const float*)d_in[17]};
  const float* gbe[4] = {(const float*)d_in[6],  (const float*)d_in[10],
                         (const float*)d_in[14], (const float*)d_in[18]};
  const float* Wih0 = (const float*)d_in[19];
  const float* Whh0 = (const float*)d_in[20];
  const float* b0   = (const float*)d_in[21];
  const float* WihR = (const float*)d_in[22];
  const float* WhhR = (const float*)d_in[23];
  const float* bR   = (const float*)d_in[24];
  const float* linW = (const float*)d_in[25];
  const float* linb = (const float*)d_in[26];
  float* out = (float*)d_out;

  char* base = (char*)d_ws;
  size_t off = 0;
  auto allocf = [&](size_t n) { float* p = (float*)(base + off); off += n * sizeof(float); return p; };
  float* xa    = allocf(6400000);
  float* xb    = allocf(6400000);
  float* ginWT = allocf(65536);
  _Float16* WT0h = (_Float16*)(base + off); off += 196608 * 2;
  _Float16* WTRh = (_Float16*)(base + off); off += 393216 * 2;
  float* bc0   = allocf(512);
  float* bcR   = allocf(1536);
  float* ebuf  = allocf(50000);
  // ---- zero region: stats only (1024 floats = 256 float4) ----
  float* stats = allocf(1024);     // 4 x (sum128|sq128)
  // ---- ints (all fully written before read; no zeroing needed) ----
  int* row_start = (int*)(base + off); off += 50004 * 4;
  int* gptr = (int*)(base + off); off += 260 * 4;
  int* csr = (int*)(base + off); off += 800000 * 4;
  int* packed = (int*)(base + off); off += 800000 * 4;
  int* partial = (int*)(base + off); off += NBIN * NBLK * 4;
  int* block_base = (int*)(base + off); off += NBIN * NBLK * 4;
  int* total = (int*)(base + off); off += 256 * 4;
  int* coarse_base = (int*)(base + off); off += 260 * 4;
  (void)ws_size; (void)in_sizes; (void)n_in; (void)out_size;

  // merged prep: zero | gptr | hist | weight repack  (grid 1+196+196+2568)
  prep_all_kernel<<<2961, 256, 0, stream>>>(batch, ei, gW[0], gW[1], gW[2], gW[3],
                                            Wih0, Whh0, WihR, WhhR, b0, bR,
                                            stats, gptr, partial, ginWT, WT0h, WTRh,
                                            bc0, bcR);
  scan_partials_kernel<<<NBIN, 256, 0, stream>>>(partial, block_base, total);
  scan_totals_kernel<<<1, 256, 0, stream>>>(total, coarse_base);
  bucket_scatter_kernel<<<NBLK, 256, 0, stream>>>(ei, coarse_base, block_base, packed);
  csr_finalize_kernel<<<NBIN, 256, 0, stream>>>(packed, coarse_base, row_start, csr);

  // GIN layer 1
  gin_agg_kernel<false><<<12500, 256, 0, stream>>>(x, row_start, csr,
                                                   nullptr, nullptr, nullptr, xb);
  gemm_gin_kernel<false><<<1564, 256, 0, stream>>>(xb, ginWT + 0 * 16384, gb[0],
                                                   nullptr, nullptr, nullptr,
                                                   xa, stats + 0, stats + 128, NN);
  gemm_gin_kernel<true><<<1564, 256, 0, stream>>>(xa, ginWT + 1 * 16384, gb[1],
                                                  stats + 0, gga[0], gbe[0],
                                                  xb, stats + 256, stats + 384, NN);
  // GIN layer 2 (BN2 finalize+affine+relu fused into the gather)
  gin_agg_kernel<true><<<12500, 256, 0, stream>>>(xb, row_start, csr,
                                                  stats + 256, gga[1], gbe[1], xa);
  gemm_gin_kernel<false><<<1564, 256, 0, stream>>>(xa, ginWT + 2 * 16384, gb[2],
                                                   nullptr, nullptr, nullptr,
                                                   xb, stats + 512, stats + 640, NN);
  gemm_gin_kernel<true><<<1564, 256, 0, stream>>>(xb, ginWT + 3 * 16384, gb[3],
                                                  stats + 512, gga[2], gbe[2],
                                                  xa, stats + 768, stats + 896, NN);
  // xa holds pre-BN4 features; BN4 fused into set2set x staging

  // fused Set2Set v7: fdot2 via float4 weight loads (scalar bitcasts only)
  set2set_kernel<<<256, 1024, 0, stream>>>(xa, gptr, stats + 768, gga[3], gbe[3],
                                           WT0h, WTRh, bc0, bcR, ebuf, linW, linb, out);
}

// Round 14
// 552.223 us; speedup vs baseline: 1.4294x; 1.4294x over previous
//
#include <hip/hip_runtime.h>
#include <math.h>

#define NN 50000
#define EE 800000
#define BBG 256
#define HHC 128
#define SEG_CAP 224  // LDS x-cache rows per graph
#define ESC 512      // per-graph e-cache entries in LDS
#define NBIN 196     // coarse bins of 256 nodes
#define NBLK 196     // blocks in K1/K3 (4096 edges each)

typedef _Float16 half8 __attribute__((ext_vector_type(8)));

__device__ __forceinline__ float4 aff4(float4 v, float4 sc, float4 sh) {
  v.x = fmaxf(fmaf(v.x, sc.x, sh.x), 0.f);
  v.y = fmaxf(fmaf(v.y, sc.y, sh.y), 0.f);
  v.z = fmaxf(fmaf(v.z, sc.z, sh.z), 0.f);
  v.w = fmaxf(fmaf(v.w, sc.w, sh.w), 0.f);
  return v;
}
__device__ __forceinline__ void add4(float4& a, float4 b) {
  a.x += b.x; a.y += b.y; a.z += b.z; a.w += b.w;
}

// ---------------- merged prep: zero | gptr | coarse hist | weight repack ----------------
// LSTM weights -> fp16, gate-interleaved (col op=4j+g), k-major [K][512]
__global__ __launch_bounds__(256) void prep_all_kernel(
    const int* __restrict__ batch,
    const int* __restrict__ ei,
    const float* __restrict__ W0, const float* __restrict__ W1,
    const float* __restrict__ W2, const float* __restrict__ W3,
    const float* __restrict__ Wih0, const float* __restrict__ Whh0,
    const float* __restrict__ WihR, const float* __restrict__ WhhR,
    const float* __restrict__ b0, const float* __restrict__ bR,
    float* __restrict__ stats, int* __restrict__ gptr, int* __restrict__ partial,
    float* __restrict__ ginWT, _Float16* __restrict__ WT0h,
    _Float16* __restrict__ WTRh, float* __restrict__ bc0, float* __restrict__ bcR) {
  __shared__ int hist[NBIN];
  int blk = blockIdx.x, tid = threadIdx.x;
  if (blk == 0) {
    ((float4*)stats)[tid] = make_float4(0.f, 0.f, 0.f, 0.f);  // 1024 floats
    return;
  }
  if (blk <= 196) {  // gptr boundaries
    int i = (blk - 1) * 256 + tid;
    if (i >= NN) return;
    int b = batch[i];
    int prev = (i == 0) ? -1 : batch[i - 1];
    for (int g = prev + 1; g <= b; ++g) gptr[g] = i;
    if (i == NN - 1) {
      for (int g = b + 1; g <= BBG; ++g) gptr[g] = NN;
    }
    return;
  }
  if (blk <= 392) {  // coarse hist
    int b = blk - 197;
    if (tid < NBIN) hist[tid] = 0;
    __syncthreads();
    const int4* dst4 = (const int4*)(ei + EE);
#pragma unroll
    for (int c = 0; c < 4; ++c) {
      int idx = b * 1024 + c * 256 + tid;
      if (idx < EE / 4) {
        int4 d = dst4[idx];
        atomicAdd(&hist[d.x >> 8], 1);
        atomicAdd(&hist[d.y >> 8], 1);
        atomicAdd(&hist[d.z >> 8], 1);
        atomicAdd(&hist[d.w >> 8], 1);
      }
    }
    __syncthreads();
    if (tid < NBIN) partial[tid * NBLK + b] = hist[tid];
    return;
  }
  // weight prep
  int idx = (blk - 393) * 256 + tid;  // [0, 657408)
  if (idx < 65536) {
    int m = idx >> 14;
    int r = idx & 16383;
    int k = r >> 7, o = r & 127;
    const float* W = (m == 0) ? W0 : (m == 1) ? W1 : (m == 2) ? W2 : W3;
    ginWT[idx] = W[o * 128 + k];
  } else if (idx < 262144) {
    int t = idx - 65536;
    int k = t >> 9, op = t & 511;
    int j = op >> 2, g = op & 3;
    int row = g * 128 + j;
    float v = (k < 256) ? Wih0[row * 256 + k] : Whh0[row * 128 + (k - 256)];
    WT0h[t] = (_Float16)v;
  } else if (idx < 655360) {
    int t = idx - 262144;
    int l = t >> 17;
    int rem = t & 131071;
    int k = rem >> 9, op = rem & 511;
    int j = op >> 2, g = op & 3;
    int row = g * 128 + j;
    float v = (k < 128) ? WihR[((size_t)l * 512 + row) * 128 + k]
                        : WhhR[((size_t)l * 512 + row) * 128 + (k - 128)];
    WTRh[t] = (_Float16)v;
  } else {
    int t = idx - 655360;
    if (t < 512) {
      bc0[t] = b0[(t & 3) * 128 + (t >> 2)];
    } else {
      int u = t - 512;
      int l = u >> 9, op = u & 511;
      bcR[u] = bR[l * 512 + (op & 3) * 128 + (op >> 2)];
    }
  }
}

// ---- atomic-free CSR build (two-level counting sort) ----

__global__ void scan_partials_kernel(const int* __restrict__ partial,
                                     int* __restrict__ block_base, int* __restrict__ total) {
  __shared__ int buf[256];
  int bin = blockIdx.x, tid = threadIdx.x;
  int v = (tid < NBLK) ? partial[bin * NBLK + tid] : 0;
  buf[tid] = v;
  __syncthreads();
  for (int off = 1; off < 256; off <<= 1) {
    int t = (tid >= off) ? buf[tid - off] : 0;
    __syncthreads();
    buf[tid] += t;
    __syncthreads();
  }
  if (tid < NBLK) block_base[bin * NBLK + tid] = buf[tid] - v;
  if (tid == 255) total[bin] = buf[255];
}

__global__ void scan_totals_kernel(const int* __restrict__ total, int* __restrict__ coarse_base) {
  __shared__ int buf[256];
  int tid = threadIdx.x;
  int v = (tid < NBIN) ? total[tid] : 0;
  buf[tid] = v;
  __syncthreads();
  for (int off = 1; off < 256; off <<= 1) {
    int t = (tid >= off) ? buf[tid - off] : 0;
    __syncthreads();
    buf[tid] += t;
    __syncthreads();
  }
  if (tid < NBIN) coarse_base[tid] = buf[tid] - v;
  if (tid == 255) coarse_base[NBIN] = buf[255];
}

__global__ __launch_bounds__(256) void bucket_scatter_kernel(const int* __restrict__ ei,
                                                             const int* __restrict__ coarse_base,
                                                             const int* __restrict__ block_base,
                                                             int* __restrict__ packed) {
  __shared__ int cursor[NBIN];
  int tid = threadIdx.x, b = blockIdx.x;
  if (tid < NBIN) cursor[tid] = coarse_base[tid] + block_base[tid * NBLK + b];
  __syncthreads();
  const int4* src4 = (const int4*)ei;
  const int4* dst4 = (const int4*)(ei + EE);
#pragma unroll
  for (int c = 0; c < 4; ++c) {
    int idx = b * 1024 + c * 256 + tid;
    if (idx < EE / 4) {
      int4 s = src4[idx];
      int4 d = dst4[idx];
      int p;
      p = atomicAdd(&cursor[d.x >> 8], 1); packed[p] = (s.x << 8) | (d.x & 255);
      p = atomicAdd(&cursor[d.y >> 8], 1); packed[p] = (s.y << 8) | (d.y & 255);
      p = atomicAdd(&cursor[d.z >> 8], 1); packed[p] = (s.z << 8) | (d.z & 255);
      p = atomicAdd(&cursor[d.w >> 8], 1); packed[p] = (s.w << 8) | (d.w & 255);
    }
  }
}

__global__ __launch_bounds__(256) void csr_finalize_kernel(const int* __restrict__ packed,
                                                           const int* __restrict__ coarse_base,
                                                           int* __restrict__ row_start,
                                                           int* __restrict__ csr) {
  __shared__ int fh[256];
  __shared__ int fb[256];
  int bin = blockIdx.x, tid = threadIdx.x;
  int e0 = coarse_base[bin], e1 = coarse_base[bin + 1];
  fh[tid] = 0;
  __syncthreads();
  for (int e = e0 + tid; e < e1; e += 256) atomicAdd(&fh[packed[e] & 255], 1);
  __syncthreads();
  int v = fh[tid];
  fb[tid] = v;
  __syncthreads();
  for (int off = 1; off < 256; off <<= 1) {
    int t = (tid >= off) ? fb[tid - off] : 0;
    __syncthreads();
    fb[tid] += t;
    __syncthreads();
  }
  int excl = fb[tid] - v;
  int node = bin * 256 + tid;
  if (node < NN) row_start[node] = e0 + excl;
  if (bin == NBIN - 1 && tid == 0) row_start[NN] = EE;
  __syncthreads();
  fb[tid] = excl;  // cursor
  __syncthreads();
  for (int e = e0 + tid; e < e1; e += 256) {
    int p = packed[e];
    int pos = atomicAdd(&fb[p & 255], 1);
    csr[e0 + pos] = p >> 8;
  }
}

// ---------------- GIN ----------------

// one wave per node; each 32-lane half loads a full 512B row as float4.
template <bool AFF>
__global__ __launch_bounds__(256) void gin_agg_kernel(
    const float* __restrict__ xin, const int* __restrict__ row_start,
    const int* __restrict__ csr,
    const float* __restrict__ stats, const float* __restrict__ gamma,
    const float* __restrict__ beta, float* __restrict__ outp) {
  __shared__ float sc_s[128], sh_s[128];
  if (AFF) {
    int t = threadIdx.x;
    if (t < 128) {
      const float invN = 1.0f / (float)NN;
      float mm = stats[t] * invN;
      float vv = stats[128 + t] * invN - mm * mm;
      float rs = rsqrtf(vv + 1e-5f);
      float sc = gamma[t] * rs;
      sc_s[t] = sc;
      sh_s[t] = beta[t] - mm * sc;
    }
    __syncthreads();
  }
  int node = blockIdx.x * 4 + (threadIdx.x >> 6);  // exact: 12500*4 = 50000
  int lane = threadIdx.x & 63;
  int half = lane >> 5, ln = lane & 31;
  const float4* x4 = (const float4*)xin;
  float4 sc4 = make_float4(0.f, 0.f, 0.f, 0.f), sh4 = sc4;
  if (AFF) {
    sc4 = *(const float4*)&sc_s[4 * ln];
    sh4 = *(const float4*)&sh_s[4 * ln];
  }
  int s0 = row_start[node], s1 = row_start[node + 1];
  float4 self = x4[(size_t)node * 32 + ln];
  if (AFF) self = aff4(self, sc4, sh4);
  float4 c0 = make_float4(0.f, 0.f, 0.f, 0.f), c1 = c0, c2 = c0, c3 = c0;
  int cnt = s1 - s0;
  int mainEnd = s0 + (cnt & ~15);
  for (int j = s0; j < mainEnd; j += 16) {
    int i0 = csr[j + half + 0];
    int i1 = csr[j + half + 2];
    int i2 = csr[j + half + 4];
    int i3 = csr[j + half + 6];
    int i4 = csr[j + half + 8];
    int i5 = csr[j + half + 10];
    int i6 = csr[j + half + 12];
    int i7 = csr[j + half + 14];
    float4 v0 = x4[(size_t)i0 * 32 + ln];
    float4 v1 = x4[(size_t)i1 * 32 + ln];
    float4 v2 = x4[(size_t)i2 * 32 + ln];
    float4 v3 = x4[(size_t)i3 * 32 + ln];
    float4 v4 = x4[(size_t)i4 * 32 + ln];
    float4 v5 = x4[(size_t)i5 * 32 + ln];
    float4 v6 = x4[(size_t)i6 * 32 + ln];
    float4 v7 = x4[(size_t)i7 * 32 + ln];
    if (AFF) {
      v0 = aff4(v0, sc4, sh4); v1 = aff4(v1, sc4, sh4);
      v2 = aff4(v2, sc4, sh4); v3 = aff4(v3, sc4, sh4);
      v4 = aff4(v4, sc4, sh4); v5 = aff4(v5, sc4, sh4);
      v6 = aff4(v6, sc4, sh4); v7 = aff4(v7, sc4, sh4);
    }
    add4(c0, v0); add4(c1, v1); add4(c2, v2); add4(c3, v3);
    add4(c0, v4); add4(c1, v5); add4(c2, v6); add4(c3, v7);
  }
  for (int j = mainEnd + half; j < s1; j += 2) {
    int i = csr[j];
    float4 v = x4[(size_t)i * 32 + ln];
    if (AFF) v = aff4(v, sc4, sh4);
    add4(c0, v);
  }
  float4 t;
  t.x = (c0.x + c1.x) + (c2.x + c3.x);
  t.y = (c0.y + c1.y) + (c2.y + c3.y);
  t.z = (c0.z + c1.z) + (c2.z + c3.z);
  t.w = (c0.w + c1.w) + (c2.w + c3.w);
  t.x += __shfl_xor(t.x, 32);
  t.y += __shfl_xor(t.y, 32);
  t.z += __shfl_xor(t.z, 32);
  t.w += __shfl_xor(t.w, 32);
  t.x += self.x; t.y += self.y; t.z += self.z; t.w += self.w;
  if (half == 0) ((float4*)outp)[(size_t)node * 32 + ln] = t;
}

// C = f(A) @ W^T + b, f = optional fused BN(stats)+relu; per-channel stats atomics.
template <bool BN>
__global__ __launch_bounds__(256) void gemm_gin_kernel(
    const float* __restrict__ A, const float* __restrict__ WT,
    const float* __restrict__ bias,
    const float* __restrict__ stats, const float* __restrict__ gamma,
    const float* __restrict__ beta,
    float* __restrict__ C,
    float* __restrict__ ssum, float* __restrict__ ssq, int M) {
  __shared__ float As[64][132];
  __shared__ float Wt[128][68];
  __shared__ float bsc[128], bsh[128];
  int tid = threadIdx.x;
  if (BN) {
    if (tid < 128) {
      const float invN = 1.0f / (float)NN;
      float mm = stats[tid] * invN;
      float vv = stats[128 + tid] * invN - mm * mm;
      float rs = rsqrtf(vv + 1e-5f);
      float sc = gamma[tid] * rs;
      bsc[tid] = sc;
      bsh[tid] = beta[tid] - mm * sc;
    }
    __syncthreads();
  }
  int tx = tid & 15, ty = tid >> 4;
  int bx = blockIdx.x & 1, by = blockIdx.x >> 1;
  int row0 = by * 64, c0 = bx * 64;
#pragma unroll
  for (int i = 0; i < 8; ++i) {
    int slot = tid + i * 256;
    int r = slot >> 5, k4 = (slot & 31) << 2;
    float4 v = make_float4(0.f, 0.f, 0.f, 0.f);
    if (row0 + r < M) v = *(const float4*)(A + (size_t)(row0 + r) * 128 + k4);
    if (BN) {
      v.x = fmaxf(fmaf(v.x, bsc[k4 + 0], bsh[k4 + 0]), 0.f);
      v.y = fmaxf(fmaf(v.y, bsc[k4 + 1], bsh[k4 + 1]), 0.f);
      v.z = fmaxf(fmaf(v.z, bsc[k4 + 2], bsh[k4 + 2]), 0.f);
      v.w = fmaxf(fmaf(v.w, bsc[k4 + 3], bsh[k4 + 3]), 0.f);
    }
    *(float4*)&As[r][k4] = v;
  }
#pragma unroll
  for (int i = 0; i < 8; ++i) {
    int slot = tid + i * 256;
    int k = slot >> 4, c4 = (slot & 15) << 2;
    *(float4*)&Wt[k][c4] = *(const float4*)(WT + (size_t)k * 128 + c0 + c4);
  }
  __syncthreads();
  float acc[4][4];
#pragma unroll
  for (int i = 0; i < 4; ++i)
#pragma unroll
    for (int j = 0; j < 4; ++j) acc[i][j] = 0.f;
#pragma unroll 4
  for (int kk = 0; kk < 128; kk += 4) {
    float4 w0 = *(const float4*)&Wt[kk + 0][tx << 2];
    float4 w1 = *(const float4*)&Wt[kk + 1][tx << 2];
    float4 w2 = *(const float4*)&Wt[kk + 2][tx << 2];
    float4 w3 = *(const float4*)&Wt[kk + 3][tx << 2];
#pragma unroll
    for (int i = 0; i < 4; ++i) {
      float4 a = *(const float4*)&As[(ty << 2) + i][kk];
      acc[i][0] += a.x * w0.x + a.y * w1.x + a.z * w2.x + a.w * w3.x;
      acc[i][1] += a.x * w0.y + a.y * w1.y + a.z * w2.y + a.w * w3.y;
      acc[i][2] += a.x * w0.z + a.y * w1.z + a.z * w2.z + a.w * w3.z;
      acc[i][3] += a.x * w0.w + a.y * w1.w + a.z * w2.w + a.w * w3.w;
    }
  }
  __syncthreads();
  float b0v = bias[c0 + (tx << 2) + 0];
  float b1v = bias[c0 + (tx << 2) + 1];
  float b2v = bias[c0 + (tx << 2) + 2];
  float b3v = bias[c0 + (tx << 2) + 3];
  float psum[4] = {0.f, 0.f, 0.f, 0.f}, psq[4] = {0.f, 0.f, 0.f, 0.f};
#pragma unroll
  for (int i = 0; i < 4; ++i) {
    int r = row0 + (ty << 2) + i;
    if (r < M) {
      float4 v;
      v.x = acc[i][0] + b0v; v.y = acc[i][1] + b1v;
      v.z = acc[i][2] + b2v; v.w = acc[i][3] + b3v;
      *(float4*)(C + (size_t)r * 128 + c0 + (tx << 2)) = v;
      psum[0] += v.x; psum[1] += v.y; psum[2] += v.z; psum[3] += v.w;
      psq[0] += v.x * v.x; psq[1] += v.y * v.y; psq[2] += v.z * v.z; psq[3] += v.w * v.w;
    }
  }
  float* red = &As[0][0];
#pragma unroll
  for (int j = 0; j < 4; ++j) {
    red[ty * 68 + (tx << 2) + j] = psum[j];
    red[1088 + ty * 68 + (tx << 2) + j] = psq[j];
  }
  __syncthreads();
  if (tid < 64) {
    float s = 0.f, sq = 0.f;
#pragma unroll
    for (int t = 0; t < 16; ++t) { s += red[t * 68 + tid]; sq += red[1088 + t * 68 + tid]; }
    atomicAdd(&ssum[c0 + tid], s);
    atomicAdd(&ssq[c0 + tid], sq);
  }
}

// ---------------- fused Set2Set v4 (round-8 proven): fp16 weights, LDS x-cache -------
// Mat-vec: 16 K-slices x 64 col-groups (8 cols each); half8 (16B) coalesced loads.
// Slice start rotated per block. Gate reduce across 512 threads.
__global__ void __launch_bounds__(1024) set2set_kernel(
    const float* __restrict__ x, const int* __restrict__ gptr,
    const float* __restrict__ stats, const float* __restrict__ gamma,
    const float* __restrict__ beta,
    const _Float16* __restrict__ WT0h, const _Float16* __restrict__ WTRh,
    const float* __restrict__ bc0, const float* __restrict__ bcR,
    float* __restrict__ ebuf,
    const float* __restrict__ linW, const float* __restrict__ linb,
    float* __restrict__ out) {
  __shared__ float xs[SEG_CAP * 128];  // 114688 B
  __shared__ float wpart[16][512];     // 32 KB (aliased as rpart in attention)
  __shared__ float gates[512];
  __shared__ float inp_s[384];
  __shared__ float hcs[4][128];
  __shared__ float ccs[4][128];
  __shared__ float qst[256];
  __shared__ float es[ESC];            // 2 KB
  __shared__ float bsc[128], bsh[128];
  __shared__ float wred[16];
  __shared__ float smax_s, ssum_s;
  __shared__ float fred[2][4];

  int g = blockIdx.x, tid = threadIdx.x;
  int w16 = tid >> 6, lane = tid & 63;

  // init
  if (tid < 128) {
    const float invN = 1.0f / (float)NN;
    float mm = stats[tid] * invN;
    float vv = stats[128 + tid] * invN - mm * mm;
    float rs = rsqrtf(vv + 1e-5f);
    float sc = gamma[tid] * rs;
    bsc[tid] = sc;
    bsh[tid] = beta[tid] - mm * sc;
#pragma unroll
    for (int l = 0; l < 4; ++l) { hcs[l][tid] = 0.f; ccs[l][tid] = 0.f; }
  }
  if (tid < 256) qst[tid] = 0.f;
  __syncthreads();

  int s0 = gptr[g], s1 = gptr[g + 1];
  int seg = s1 - s0;
  int ncache = seg < SEG_CAP ? seg : SEG_CAP;
  const float2* x2 = (const float2*)x;
  float sc0 = bsc[2 * lane], sc1 = bsc[2 * lane + 1];
  float sh0 = bsh[2 * lane], sh1 = bsh[2 * lane + 1];
  // stage segment into LDS once (BN4-transformed); one row per wave
  for (int n = w16; n < ncache; n += 16) {
    float2 v = x2[(size_t)(s0 + n) * 64 + lane];
    xs[n * 128 + 2 * lane] = fmaxf(fmaf(v.x, sc0, sh0), 0.f);
    xs[n * 128 + 2 * lane + 1] = fmaxf(fmaf(v.y, sc1, sh1), 0.f);
  }
  __syncthreads();

  int s_ = tid >> 6, cg = tid & 63;  // matvec: K-slice (16), col-group (8 cols)

  for (int step = 0; step < 4; ++step) {
    // ---- 4 stacked LSTM cells ----
    for (int cell = 0; cell < 4; ++cell) {
      const _Float16* WTh; const float* bias; int K;
      if (cell == 0) {
        WTh = WT0h; bias = bc0; K = 384;
        if (tid < 256) inp_s[tid] = qst[tid];
        else if (tid < 384) inp_s[tid] = hcs[0][tid - 256];
      } else {
        WTh = WTRh + (size_t)(cell - 1) * 131072;
        bias = bcR + (cell - 1) * 512; K = 256;
        if (tid < 128) inp_s[tid] = hcs[cell - 1][tid];
        else if (tid < 256) inp_s[tid] = hcs[cell][tid - 128];
      }
      __syncthreads();
      int kper = K >> 4;
      int se = (s_ + g) & 15;           // rotate slice start per block
      int k0 = se * kper;
      const _Float16* wp = WTh + 8 * cg;
      float a[8] = {0.f, 0.f, 0.f, 0.f, 0.f, 0.f, 0.f, 0.f};
      for (int k = k0; k < k0 + kper; k += 8) {
        half8 w0 = *(const half8*)(wp + (size_t)(k + 0) * 512);
        half8 w1 = *(const half8*)(wp + (size_t)(k + 1) * 512);
        half8 w2 = *(const half8*)(wp + (size_t)(k + 2) * 512);
        half8 w3 = *(const half8*)(wp + (size_t)(k + 3) * 512);
        half8 w4 = *(const half8*)(wp + (size_t)(k + 4) * 512);
        half8 w5 = *(const half8*)(wp + (size_t)(k + 5) * 512);
        half8 w6 = *(const half8*)(wp + (size_t)(k + 6) * 512);
        half8 w7 = *(const half8*)(wp + (size_t)(k + 7) * 512);
        float i0 = inp_s[k + 0], i1 = inp_s[k + 1], i2 = inp_s[k + 2], i3 = inp_s[k + 3];
        float i4 = inp_s[k + 4], i5 = inp_s[k + 5], i6 = inp_s[k + 6], i7 = inp_s[k + 7];
#pragma unroll
        for (int j = 0; j < 8; ++j) {
          a[j] += i0 * (float)w0[j] + i1 * (float)w1[j] +
                  i2 * (float)w2[j] + i3 * (float)w3[j];
          a[j] += i4 * (float)w4[j] + i5 * (float)w5[j] +
                  i6 * (float)w6[j] + i7 * (float)w7[j];
        }
      }
#pragma unroll
      for (int j = 0; j < 8; ++j) wpart[s_][8 * cg + j] = a[j];
      __syncthreads();
      if (tid < 512) {
        float acc = bias[tid];
#pragma unroll
        for (int s = 0; s < 16; ++s) acc += wpart[s][tid];
        gates[tid] = acc;
      }
      __syncthreads();
      if (tid < 128) {
        int j = tid;
        float gi = gates[4 * j + 0];
        float gf = gates[4 * j + 1];
        float gc = gates[4 * j + 2];
        float go = gates[4 * j + 3];
        float cp = ccs[cell][j];
        float si = 1.f / (1.f + expf(-gi));
        float sf = 1.f / (1.f + expf(-gf));
        float so = 1.f / (1.f + expf(-go));
        float cn = sf * cp + si * tanhf(gc);
        ccs[cell][j] = cn;
        hcs[cell][j] = so * tanhf(cn);
      }
      __syncthreads();
    }
    // ---- attention, q = new h[3]; x from LDS cache ----
    float* rpart = &wpart[0][0];  // alias: time-disjoint with matvec
    float qx = hcs[3][2 * lane], qy = hcs[3][2 * lane + 1];
    // pass 1: e + max
    float wmax = -3.0e38f;
    for (int n = w16; n < seg; n += 16) {
      float vx, vy;
      if (n < ncache) {
        vx = xs[n * 128 + 2 * lane];
        vy = xs[n * 128 + 2 * lane + 1];
      } else {
        float2 v = x2[(size_t)(s0 + n) * 64 + lane];
        vx = fmaxf(fmaf(v.x, sc0, sh0), 0.f);
        vy = fmaxf(fmaf(v.y, sc1, sh1), 0.f);
      }
      float e = vx * qx + vy * qy;
#pragma unroll
      for (int sh = 32; sh; sh >>= 1) e += __shfl_xor(e, sh);
      if (lane == 0) { if (n < ESC) es[n] = e; else ebuf[s0 + n] = e; }
      wmax = fmaxf(wmax, e);
    }
    if (lane == 0) wred[w16] = wmax;
    __syncthreads();
    if (tid == 0) {
      float m = wred[0];
#pragma unroll
      for (int t = 1; t < 16; ++t) m = fmaxf(m, wred[t]);
      smax_s = m;
    }
    __syncthreads();
    float m = smax_s;
    // pass 2: sum exp
    float loc = 0.f;
    for (int n = tid; n < seg; n += 1024) {
      float e = (n < ESC) ? es[n] : ebuf[s0 + n];
      loc += expf(e - m);
    }
#pragma unroll
    for (int sh = 32; sh; sh >>= 1) loc += __shfl_xor(loc, sh);
    __syncthreads();
    if (lane == 0) wred[w16] = loc;
    __syncthreads();
    if (tid == 0) {
      float s = 0.f;
#pragma unroll
      for (int t = 0; t < 16; ++t) s += wred[t];
      ssum_s = s;
    }
    __syncthreads();
    float inv = 1.0f / ssum_s;
    // pass 3: r = sum a*x
    float rx = 0.f, ry = 0.f;
    for (int n = w16; n < seg; n += 16) {
      float e = (n < ESC) ? es[n] : ebuf[s0 + n];
      float coef = expf(e - m) * inv;
      float vx, vy;
      if (n < ncache) {
        vx = xs[n * 128 + 2 * lane];
        vy = xs[n * 128 + 2 * lane + 1];
      } else {
        float2 v = x2[(size_t)(s0 + n) * 64 + lane];
        vx = fmaxf(fmaf(v.x, sc0, sh0), 0.f);
        vy = fmaxf(fmaf(v.y, sc1, sh1), 0.f);
      }
      rx += coef * vx; ry += coef * vy;
    }
    rpart[w16 * 128 + 2 * lane] = rx;
    rpart[w16 * 128 + 2 * lane + 1] = ry;
    __syncthreads();
    if (tid < 128) {
      float r = 0.f;
#pragma unroll
      for (int t = 0; t < 16; ++t) r += rpart[t * 128 + tid];
      qst[tid] = hcs[3][tid];
      qst[128 + tid] = r;
    }
    __syncthreads();
  }
  // ---- final linear ----
  if (tid < 256) {
    float val = qst[tid];
    float p0 = val * linW[tid];
    float p1 = val * linW[256 + tid];
#pragma unroll
    for (int sh = 32; sh; sh >>= 1) { p0 += __shfl_xor(p0, sh); p1 += __shfl_xor(p1, sh); }
    if (lane == 0) { fred[0][w16] = p0; fred[1][w16] = p1; }
  }
  __syncthreads();
  if (tid == 0) {
    out[2 * g + 0] = fred[0][0] + fred[0][1] + fred[0][2] + fred[0][3] + linb[0];
    out[2 * g + 1] = fred[1][0] + fred[1][1] + fred[1][2] + fred[1][3] + linb[1];
  }
}

// ---------------- launch ----------------

extern "C" void kernel_launch(void* const* d_in, const int* in_sizes, int n_in,
                              void* d_out, int out_size, void* d_ws, size_t ws_size,
                              hipStream_t stream) {
  const float* x = (const float*)d_in[0];
  const int* ei = (const int*)d_in[1];
  const int* batch = (const int*)d_in[2];
  const float* gW[4]  = {(const float*)d_in[3],  (const float*)d_in[7],
                         (const float*)d_in[11], (const float*)d_in[15]};
  const float* gb[4]  = {(const float*)d_in[4],  (const float*)d_in[8],
                         (const float*)d_in[12], (const float*)d_in[16]};
  const float* gga[4] = {(const float*)d_in[5],  (const float*)d_in[9],
                         (const float*)d_in[13], (const float*)d_in[17]};
  const float* gbe[4] = {(const float*)d_in[6],  (const float*)d_in[10],
                         (const float*)d_in[14], (const float*)d_in[18]};
  const float* Wih0 = (const float*)d_in[19];
  const float* Whh0 = (const float*)d_in[20];
  const float* b0   = (const float*)d_in[21];
  const float* WihR = (const float*)d_in[22];
  const float* WhhR = (const float*)d_in[23];
  const float* bR   = (const float*)d_in[24];
  const float* linW = (const float*)d_in[25];
  const float* linb = (const float*)d_in[26];
  float* out = (float*)d_out;

  char* base = (char*)d_ws;
  size_t off = 0;
  auto allocf = [&](size_t n) { float* p = (float*)(base + off); off += n * sizeof(float); return p; };
  float* xa    = allocf(6400000);
  float* xb    = allocf(6400000);
  float* ginWT = allocf(65536);
  _Float16* WT0h = (_Float16*)(base + off); off += 196608 * 2;
  _Float16* WTRh = (_Float16*)(base + off); off += 393216 * 2;
  float* bc0   = allocf(512);
  float* bcR   = allocf(1536);
  float* ebuf  = allocf(50000);
  // ---- zero region: stats only (1024 floats = 256 float4) ----
  float* stats = allocf(1024);     // 4 x (sum128|sq128)
  // ---- ints (all fully written before read; no zeroing needed) ----
  int* row_start = (int*)(base + off); off += 50004 * 4;
  int* gptr = (int*)(base + off); off += 260 * 4;
  int* csr = (int*)(base + off); off += 800000 * 4;
  int* packed = (int*)(base + off); off += 800000 * 4;
  int* partial = (int*)(base + off); off += NBIN * NBLK * 4;
  int* block_base = (int*)(base + off); off += NBIN * NBLK * 4;
  int* total = (int*)(base + off); off += 256 * 4;
  int* coarse_base = (int*)(base + off); off += 260 * 4;
  (void)ws_size; (void)in_sizes; (void)n_in; (void)out_size;

  // merged prep: zero | gptr | hist | weight repack  (grid 1+196+196+2568)
  prep_all_kernel<<<2961, 256, 0, stream>>>(batch, ei, gW[0], gW[1], gW[2], gW[3],
                                            Wih0, Whh0, WihR, WhhR, b0, bR,
                                            stats, gptr, partial, ginWT, WT0h, WTRh,
                                            bc0, bcR);
  scan_partials_kernel<<<NBIN, 256, 0, stream>>>(partial, block_base, total);
  scan_totals_kernel<<<1, 256, 0, stream>>>(total, coarse_base);
  bucket_scatter_kernel<<<NBLK, 256, 0, stream>>>(ei, coarse_base, block_base, packed);
  csr_finalize_kernel<<<NBIN, 256, 0, stream>>>(packed, coarse_base, row_start, csr);

  // GIN layer 1
  gin_agg_kernel<false><<<12500, 256, 0, stream>>>(x, row_start, csr,
                                                   nullptr, nullptr, nullptr, xb);
  gemm_gin_kernel<false><<<1564, 256, 0, stream>>>(xb, ginWT + 0 * 16384, gb[0],
                                                   nullptr, nullptr, nullptr,
                                                   xa, stats + 0, stats + 128, NN);
  gemm_gin_kernel<true><<<1564, 256, 0, stream>>>(xa, ginWT + 1 * 16384, gb[1],
                                                  stats + 0, gga[0], gbe[0],
                                                  xb, stats + 256, stats + 384, NN);
  // GIN layer 2 (BN2 finalize+affine+relu fused into the gather)
  gin_agg_kernel<true><<<12500, 256, 0, stream>>>(xb, row_start, csr,
                                                  stats + 256, gga[1], gbe[1], xa);
  gemm_gin_kernel<false><<<1564, 256, 0, stream>>>(xa, ginWT + 2 * 16384, gb[2],
                                                   nullptr, nullptr, nullptr,
                                                   xb, stats + 512, stats + 640, NN);
  gemm_gin_kernel<true><<<1564, 256, 0, stream>>>(xb, ginWT + 3 * 16384, gb[3],
                                                  stats + 512, gga[2], gbe[2],
                                                  xa, stats + 768, stats + 896, NN);
  // xa holds pre-BN4 features; BN4 fused into set2set x staging

  // fused Set2Set v4 (round-8 proven): fp16 weights, 1 graph/block, LDS x-cache
  set2set_kernel<<<256, 1024, 0, stream>>>(xa, gptr, stats + 768, gga[3], gbe[3],
                                           WT0h, WTRh, bc0, bcR, ebuf, linW, linb, out);
}

// Round 15
// 517.435 us; speedup vs baseline: 1.5255x; 1.0672x over previous
//
#include <hip/hip_runtime.h>
#include <math.h>

#define NN 50000
#define EE 800000
#define BBG 256
#define HHC 128
#define SEG_CAP 224  // LDS x-cache rows per graph
#define ESC 512      // per-graph e-cache entries in LDS
#define NBIN 196     // coarse bins of 256 nodes
#define NBLK 196     // blocks in K1/K3 (4096 edges each)

typedef _Float16 half8 __attribute__((ext_vector_type(8)));
typedef _Float16 half4 __attribute__((ext_vector_type(4)));

__device__ __forceinline__ float4 aff4(float4 v, float4 sc, float4 sh) {
  v.x = fmaxf(fmaf(v.x, sc.x, sh.x), 0.f);
  v.y = fmaxf(fmaf(v.y, sc.y, sh.y), 0.f);
  v.z = fmaxf(fmaf(v.z, sc.z, sh.z), 0.f);
  v.w = fmaxf(fmaf(v.w, sc.w, sh.w), 0.f);
  return v;
}
__device__ __forceinline__ void add4(float4& a, float4 b) {
  a.x += b.x; a.y += b.y; a.z += b.z; a.w += b.w;
}
__device__ __forceinline__ float4 cvt4(half4 h) {
  return make_float4((float)h[0], (float)h[1], (float)h[2], (float)h[3]);
}

// ---------------- merged prep: zero | gptr | coarse hist | weight repack | x->fp16 ----
// LSTM weights -> fp16, gate-interleaved (col op=4j+g), k-major [K][512]
__global__ __launch_bounds__(256) void prep_all_kernel(
    const int* __restrict__ batch,
    const int* __restrict__ ei,
    const float* __restrict__ W0, const float* __restrict__ W1,
    const float* __restrict__ W2, const float* __restrict__ W3,
    const float* __restrict__ Wih0, const float* __restrict__ Whh0,
    const float* __restrict__ WihR, const float* __restrict__ WhhR,
    const float* __restrict__ b0, const float* __restrict__ bR,
    const float* __restrict__ xsrc,
    float* __restrict__ stats, int* __restrict__ gptr, int* __restrict__ partial,
    float* __restrict__ ginWT, _Float16* __restrict__ WT0h,
    _Float16* __restrict__ WTRh, float* __restrict__ bc0, float* __restrict__ bcR,
    _Float16* __restrict__ x16a) {
  __shared__ int hist[NBIN];
  int blk = blockIdx.x, tid = threadIdx.x;
  if (blk == 0) {
    ((float4*)stats)[tid] = make_float4(0.f, 0.f, 0.f, 0.f);  // 1024 floats
    return;
  }
  if (blk <= 196) {  // gptr boundaries
    int i = (blk - 1) * 256 + tid;
    if (i >= NN) return;
    int b = batch[i];
    int prev = (i == 0) ? -1 : batch[i - 1];
    for (int g = prev + 1; g <= b; ++g) gptr[g] = i;
    if (i == NN - 1) {
      for (int g = b + 1; g <= BBG; ++g) gptr[g] = NN;
    }
    return;
  }
  if (blk <= 392) {  // coarse hist
    int b = blk - 197;
    if (tid < NBIN) hist[tid] = 0;
    __syncthreads();
    const int4* dst4 = (const int4*)(ei + EE);
#pragma unroll
    for (int c = 0; c < 4; ++c) {
      int idx = b * 1024 + c * 256 + tid;
      if (idx < EE / 4) {
        int4 d = dst4[idx];
        atomicAdd(&hist[d.x >> 8], 1);
        atomicAdd(&hist[d.y >> 8], 1);
        atomicAdd(&hist[d.z >> 8], 1);
        atomicAdd(&hist[d.w >> 8], 1);
      }
    }
    __syncthreads();
    if (tid < NBIN) partial[tid * NBLK + b] = hist[tid];
    return;
  }
  if (blk >= 2961) {  // x -> fp16 (6250 blocks x 256 = 1,600,000 float4 groups)
    int i = (blk - 2961) * 256 + tid;
    float4 v = ((const float4*)xsrc)[i];
    half4 h;
    h[0] = (_Float16)v.x; h[1] = (_Float16)v.y;
    h[2] = (_Float16)v.z; h[3] = (_Float16)v.w;
    ((half4*)x16a)[i] = h;
    return;
  }
  // weight prep
  int idx = (blk - 393) * 256 + tid;  // [0, 657408)
  if (idx < 65536) {
    int m = idx >> 14;
    int r = idx & 16383;
    int k = r >> 7, o = r & 127;
    const float* W = (m == 0) ? W0 : (m == 1) ? W1 : (m == 2) ? W2 : W3;
    ginWT[idx] = W[o * 128 + k];
  } else if (idx < 262144) {
    int t = idx - 65536;
    int k = t >> 9, op = t & 511;
    int j = op >> 2, g = op & 3;
    int row = g * 128 + j;
    float v = (k < 256) ? Wih0[row * 256 + k] : Whh0[row * 128 + (k - 256)];
    WT0h[t] = (_Float16)v;
  } else if (idx < 655360) {
    int t = idx - 262144;
    int l = t >> 17;
    int rem = t & 131071;
    int k = rem >> 9, op = rem & 511;
    int j = op >> 2, g = op & 3;
    int row = g * 128 + j;
    float v = (k < 128) ? WihR[((size_t)l * 512 + row) * 128 + k]
                        : WhhR[((size_t)l * 512 + row) * 128 + (k - 128)];
    WTRh[t] = (_Float16)v;
  } else {
    int t = idx - 655360;
    if (t < 512) {
      bc0[t] = b0[(t & 3) * 128 + (t >> 2)];
    } else {
      int u = t - 512;
      int l = u >> 9, op = u & 511;
      bcR[u] = bR[l * 512 + (op & 3) * 128 + (op >> 2)];
    }
  }
}

// ---- atomic-free CSR build (two-level counting sort) ----

__global__ void scan_partials_kernel(const int* __restrict__ partial,
                                     int* __restrict__ block_base, int* __restrict__ total) {
  __shared__ int buf[256];
  int bin = blockIdx.x, tid = threadIdx.x;
  int v = (tid < NBLK) ? partial[bin * NBLK + tid] : 0;
  buf[tid] = v;
  __syncthreads();
  for (int off = 1; off < 256; off <<= 1) {
    int t = (tid >= off) ? buf[tid - off] : 0;
    __syncthreads();
    buf[tid] += t;
    __syncthreads();
  }
  if (tid < NBLK) block_base[bin * NBLK + tid] = buf[tid] - v;
  if (tid == 255) total[bin] = buf[255];
}

__global__ void scan_totals_kernel(const int* __restrict__ total, int* __restrict__ coarse_base) {
  __shared__ int buf[256];
  int tid = threadIdx.x;
  int v = (tid < NBIN) ? total[tid] : 0;
  buf[tid] = v;
  __syncthreads();
  for (int off = 1; off < 256; off <<= 1) {
    int t = (tid >= off) ? buf[tid - off] : 0;
    __syncthreads();
    buf[tid] += t;
    __syncthreads();
  }
  if (tid < NBIN) coarse_base[tid] = buf[tid] - v;
  if (tid == 255) coarse_base[NBIN] = buf[255];
}

__global__ __launch_bounds__(256) void bucket_scatter_kernel(const int* __restrict__ ei,
                                                             const int* __restrict__ coarse_base,
                                                             const int* __restrict__ block_base,
                                                             int* __restrict__ packed) {
  __shared__ int cursor[NBIN];
  int tid = threadIdx.x, b = blockIdx.x;
  if (tid < NBIN) cursor[tid] = coarse_base[tid] + block_base[tid * NBLK + b];
  __syncthreads();
  const int4* src4 = (const int4*)ei;
  const int4* dst4 = (const int4*)(ei + EE);
#pragma unroll
  for (int c = 0; c < 4; ++c) {
    int idx = b * 1024 + c * 256 + tid;
    if (idx < EE / 4) {
      int4 s = src4[idx];
      int4 d = dst4[idx];
      int p;
      p = atomicAdd(&cursor[d.x >> 8], 1); packed[p] = (s.x << 8) | (d.x & 255);
      p = atomicAdd(&cursor[d.y >> 8], 1); packed[p] = (s.y << 8) | (d.y & 255);
      p = atomicAdd(&cursor[d.z >> 8], 1); packed[p] = (s.z << 8) | (d.z & 255);
      p = atomicAdd(&cursor[d.w >> 8], 1); packed[p] = (s.w << 8) | (d.w & 255);
    }
  }
}

__global__ __launch_bounds__(256) void csr_finalize_kernel(const int* __restrict__ packed,
                                                           const int* __restrict__ coarse_base,
                                                           int* __restrict__ row_start,
                                                           int* __restrict__ csr) {
  __shared__ int fh[256];
  __shared__ int fb[256];
  int bin = blockIdx.x, tid = threadIdx.x;
  int e0 = coarse_base[bin], e1 = coarse_base[bin + 1];
  fh[tid] = 0;
  __syncthreads();
  for (int e = e0 + tid; e < e1; e += 256) atomicAdd(&fh[packed[e] & 255], 1);
  __syncthreads();
  int v = fh[tid];
  fb[tid] = v;
  __syncthreads();
  for (int off = 1; off < 256; off <<= 1) {
    int t = (tid >= off) ? fb[tid - off] : 0;
    __syncthreads();
    fb[tid] += t;
    __syncthreads();
  }
  int excl = fb[tid] - v;
  int node = bin * 256 + tid;
  if (node < NN) row_start[node] = e0 + excl;
  if (bin == NBIN - 1 && tid == 0) row_start[NN] = EE;
  __syncthreads();
  fb[tid] = excl;  // cursor
  __syncthreads();
  for (int e = e0 + tid; e < e1; e += 256) {
    int p = packed[e];
    int pos = atomicAdd(&fb[p & 255], 1);
    csr[e0 + pos] = p >> 8;
  }
}

// ---------------- GIN ----------------

// one wave per node; each 32-lane half loads a full 256B fp16 row as half4/lane.
template <bool AFF>
__global__ __launch_bounds__(256) void gin_agg_kernel(
    const _Float16* __restrict__ x16, const int* __restrict__ row_start,
    const int* __restrict__ csr,
    const float* __restrict__ stats, const float* __restrict__ gamma,
    const float* __restrict__ beta, float* __restrict__ outp) {
  __shared__ float sc_s[128], sh_s[128];
  if (AFF) {
    int t = threadIdx.x;
    if (t < 128) {
      const float invN = 1.0f / (float)NN;
      float mm = stats[t] * invN;
      float vv = stats[128 + t] * invN - mm * mm;
      float rs = rsqrtf(vv + 1e-5f);
      float sc = gamma[t] * rs;
      sc_s[t] = sc;
      sh_s[t] = beta[t] - mm * sc;
    }
    __syncthreads();
  }
  int node = blockIdx.x * 4 + (threadIdx.x >> 6);  // exact: 12500*4 = 50000
  int lane = threadIdx.x & 63;
  int half = lane >> 5, ln = lane & 31;
  const half4* xh = (const half4*)x16;  // row = node*32 half4s
  float4 sc4 = make_float4(0.f, 0.f, 0.f, 0.f), sh4 = sc4;
  if (AFF) {
    sc4 = *(const float4*)&sc_s[4 * ln];
    sh4 = *(const float4*)&sh_s[4 * ln];
  }
  int s0 = row_start[node], s1 = row_start[node + 1];
  float4 self = cvt4(xh[(size_t)node * 32 + ln]);
  if (AFF) self = aff4(self, sc4, sh4);
  float4 c0 = make_float4(0.f, 0.f, 0.f, 0.f), c1 = c0, c2 = c0, c3 = c0;
  int cnt = s1 - s0;
  int mainEnd = s0 + (cnt & ~15);
  for (int j = s0; j < mainEnd; j += 16) {
    int i0 = csr[j + half + 0];
    int i1 = csr[j + half + 2];
    int i2 = csr[j + half + 4];
    int i3 = csr[j + half + 6];
    int i4 = csr[j + half + 8];
    int i5 = csr[j + half + 10];
    int i6 = csr[j + half + 12];
    int i7 = csr[j + half + 14];
    half4 h0 = xh[(size_t)i0 * 32 + ln];
    half4 h1 = xh[(size_t)i1 * 32 + ln];
    half4 h2 = xh[(size_t)i2 * 32 + ln];
    half4 h3 = xh[(size_t)i3 * 32 + ln];
    half4 h4 = xh[(size_t)i4 * 32 + ln];
    half4 h5 = xh[(size_t)i5 * 32 + ln];
    half4 h6 = xh[(size_t)i6 * 32 + ln];
    half4 h7 = xh[(size_t)i7 * 32 + ln];
    float4 v0 = cvt4(h0);
    float4 v1 = cvt4(h1);
    float4 v2 = cvt4(h2);
    float4 v3 = cvt4(h3);
    float4 v4 = cvt4(h4);
    float4 v5 = cvt4(h5);
    float4 v6 = cvt4(h6);
    float4 v7 = cvt4(h7);
    if (AFF) {
      v0 = aff4(v0, sc4, sh4); v1 = aff4(v1, sc4, sh4);
      v2 = aff4(v2, sc4, sh4); v3 = aff4(v3, sc4, sh4);
      v4 = aff4(v4, sc4, sh4); v5 = aff4(v5, sc4, sh4);
      v6 = aff4(v6, sc4, sh4); v7 = aff4(v7, sc4, sh4);
    }
    add4(c0, v0); add4(c1, v1); add4(c2, v2); add4(c3, v3);
    add4(c0, v4); add4(c1, v5); add4(c2, v6); add4(c3, v7);
  }
  for (int j = mainEnd + half; j < s1; j += 2) {
    int i = csr[j];
    float4 v = cvt4(xh[(size_t)i * 32 + ln]);
    if (AFF) v = aff4(v, sc4, sh4);
    add4(c0, v);
  }
  float4 t;
  t.x = (c0.x + c1.x) + (c2.x + c3.x);
  t.y = (c0.y + c1.y) + (c2.y + c3.y);
  t.z = (c0.z + c1.z) + (c2.z + c3.z);
  t.w = (c0.w + c1.w) + (c2.w + c3.w);
  t.x += __shfl_xor(t.x, 32);
  t.y += __shfl_xor(t.y, 32);
  t.z += __shfl_xor(t.z, 32);
  t.w += __shfl_xor(t.w, 32);
  t.x += self.x; t.y += self.y; t.z += self.z; t.w += self.w;
  if (half == 0) ((float4*)outp)[(size_t)node * 32 + ln] = t;
}

// C = f(A) @ W^T + b, f = optional fused BN(stats)+relu; per-channel stats atomics.
// Optional fp32 output (C may be null) and optional fp16 output copy (h16out).
template <bool BN>
__global__ __launch_bounds__(256) void gemm_gin_kernel(
    const float* __restrict__ A, const float* __restrict__ WT,
    const float* __restrict__ bias,
    const float* __restrict__ stats, const float* __restrict__ gamma,
    const float* __restrict__ beta,
    float* __restrict__ C, _Float16* __restrict__ h16out,
    float* __restrict__ ssum, float* __restrict__ ssq, int M) {
  __shared__ float As[64][132];
  __shared__ float Wt[128][68];
  __shared__ float bsc[128], bsh[128];
  int tid = threadIdx.x;
  if (BN) {
    if (tid < 128) {
      const float invN = 1.0f / (float)NN;
      float mm = stats[tid] * invN;
      float vv = stats[128 + tid] * invN - mm * mm;
      float rs = rsqrtf(vv + 1e-5f);
      float sc = gamma[tid] * rs;
      bsc[tid] = sc;
      bsh[tid] = beta[tid] - mm * sc;
    }
    __syncthreads();
  }
  int tx = tid & 15, ty = tid >> 4;
  int bx = blockIdx.x & 1, by = blockIdx.x >> 1;
  int row0 = by * 64, c0 = bx * 64;
#pragma unroll
  for (int i = 0; i < 8; ++i) {
    int slot = tid + i * 256;
    int r = slot >> 5, k4 = (slot & 31) << 2;
    float4 v = make_float4(0.f, 0.f, 0.f, 0.f);
    if (row0 + r < M) v = *(const float4*)(A + (size_t)(row0 + r) * 128 + k4);
    if (BN) {
      v.x = fmaxf(fmaf(v.x, bsc[k4 + 0], bsh[k4 + 0]), 0.f);
      v.y = fmaxf(fmaf(v.y, bsc[k4 + 1], bsh[k4 + 1]), 0.f);
      v.z = fmaxf(fmaf(v.z, bsc[k4 + 2], bsh[k4 + 2]), 0.f);
      v.w = fmaxf(fmaf(v.w, bsc[k4 + 3], bsh[k4 + 3]), 0.f);
    }
    *(float4*)&As[r][k4] = v;
  }
#pragma unroll
  for (int i = 0; i < 8; ++i) {
    int slot = tid + i * 256;
    int k = slot >> 4, c4 = (slot & 15) << 2;
    *(float4*)&Wt[k][c4] = *(const float4*)(WT + (size_t)k * 128 + c0 + c4);
  }
  __syncthreads();
  float acc[4][4];
#pragma unroll
  for (int i = 0; i < 4; ++i)
#pragma unroll
    for (int j = 0; j < 4; ++j) acc[i][j] = 0.f;
#pragma unroll 4
  for (int kk = 0; kk < 128; kk += 4) {
    float4 w0 = *(const float4*)&Wt[kk + 0][tx << 2];
    float4 w1 = *(const float4*)&Wt[kk + 1][tx << 2];
    float4 w2 = *(const float4*)&Wt[kk + 2][tx << 2];
    float4 w3 = *(const float4*)&Wt[kk + 3][tx << 2];
#pragma unroll
    for (int i = 0; i < 4; ++i) {
      float4 a = *(const float4*)&As[(ty << 2) + i][kk];
      acc[i][0] += a.x * w0.x + a.y * w1.x + a.z * w2.x + a.w * w3.x;
      acc[i][1] += a.x * w0.y + a.y * w1.y + a.z * w2.y + a.w * w3.y;
      acc[i][2] += a.x * w0.z + a.y * w1.z + a.z * w2.z + a.w * w3.z;
      acc[i][3] += a.x * w0.w + a.y * w1.w + a.z * w2.w + a.w * w3.w;
    }
  }
  __syncthreads();
  float b0v = bias[c0 + (tx << 2) + 0];
  float b1v = bias[c0 + (tx << 2) + 1];
  float b2v = bias[c0 + (tx << 2) + 2];
  float b3v = bias[c0 + (tx << 2) + 3];
  float psum[4] = {0.f, 0.f, 0.f, 0.f}, psq[4] = {0.f, 0.f, 0.f, 0.f};
#pragma unroll
  for (int i = 0; i < 4; ++i) {
    int r = row0 + (ty << 2) + i;
    if (r < M) {
      float4 v;
      v.x = acc[i][0] + b0v; v.y = acc[i][1] + b1v;
      v.z = acc[i][2] + b2v; v.w = acc[i][3] + b3v;
      if (C) *(float4*)(C + (size_t)r * 128 + c0 + (tx << 2)) = v;
      if (h16out) {
        half4 hv;
        hv[0] = (_Float16)v.x; hv[1] = (_Float16)v.y;
        hv[2] = (_Float16)v.z; hv[3] = (_Float16)v.w;
        *(half4*)(h16out + (size_t)r * 128 + c0 + (tx << 2)) = hv;
      }
      psum[0] += v.x; psum[1] += v.y; psum[2] += v.z; psum[3] += v.w;
      psq[0] += v.x * v.x; psq[1] += v.y * v.y; psq[2] += v.z * v.z; psq[3] += v.w * v.w;
    }
  }
  float* red = &As[0][0];
#pragma unroll
  for (int j = 0; j < 4; ++j) {
    red[ty * 68 + (tx << 2) + j] = psum[j];
    red[1088 + ty * 68 + (tx << 2) + j] = psq[j];
  }
  __syncthreads();
  if (tid < 64) {
    float s = 0.f, sq = 0.f;
#pragma unroll
    for (int t = 0; t < 16; ++t) { s += red[t * 68 + tid]; sq += red[1088 + t * 68 + tid]; }
    atomicAdd(&ssum[c0 + tid], s);
    atomicAdd(&ssq[c0 + tid], sq);
  }
}

// ---------------- fused Set2Set v4 (round-8 proven): fp16 weights, LDS x-cache -------
__global__ void __launch_bounds__(1024) set2set_kernel(
    const float* __restrict__ x, const int* __restrict__ gptr,
    const float* __restrict__ stats, const float* __restrict__ gamma,
    const float* __restrict__ beta,
    const _Float16* __restrict__ WT0h, const _Float16* __restrict__ WTRh,
    const float* __restrict__ bc0, const float* __restrict__ bcR,
    float* __restrict__ ebuf,
    const float* __restrict__ linW, const float* __restrict__ linb,
    float* __restrict__ out) {
  __shared__ float xs[SEG_CAP * 128];  // 114688 B
  __shared__ float wpart[16][512];     // 32 KB (aliased as rpart in attention)
  __shared__ float gates[512];
  __shared__ float inp_s[384];
  __shared__ float hcs[4][128];
  __shared__ float ccs[4][128];
  __shared__ float qst[256];
  __shared__ float es[ESC];            // 2 KB
  __shared__ float bsc[128], bsh[128];
  __shared__ float wred[16];
  __shared__ float smax_s, ssum_s;
  __shared__ float fred[2][4];

  int g = blockIdx.x, tid = threadIdx.x;
  int w16 = tid >> 6, lane = tid & 63;

  // init
  if (tid < 128) {
    const float invN = 1.0f / (float)NN;
    float mm = stats[tid] * invN;
    float vv = stats[128 + tid] * invN - mm * mm;
    float rs = rsqrtf(vv + 1e-5f);
    float sc = gamma[tid] * rs;
    bsc[tid] = sc;
    bsh[tid] = beta[tid] - mm * sc;
#pragma unroll
    for (int l = 0; l < 4; ++l) { hcs[l][tid] = 0.f; ccs[l][tid] = 0.f; }
  }
  if (tid < 256) qst[tid] = 0.f;
  __syncthreads();

  int s0 = gptr[g], s1 = gptr[g + 1];
  int seg = s1 - s0;
  int ncache = seg < SEG_CAP ? seg : SEG_CAP;
  const float2* x2 = (const float2*)x;
  float sc0 = bsc[2 * lane], sc1 = bsc[2 * lane + 1];
  float sh0 = bsh[2 * lane], sh1 = bsh[2 * lane + 1];
  // stage segment into LDS once (BN4-transformed); one row per wave
  for (int n = w16; n < ncache; n += 16) {
    float2 v = x2[(size_t)(s0 + n) * 64 + lane];
    xs[n * 128 + 2 * lane] = fmaxf(fmaf(v.x, sc0, sh0), 0.f);
    xs[n * 128 + 2 * lane + 1] = fmaxf(fmaf(v.y, sc1, sh1), 0.f);
  }
  __syncthreads();

  int s_ = tid >> 6, cg = tid & 63;  // matvec: K-slice (16), col-group (8 cols)

  for (int step = 0; step < 4; ++step) {
    // ---- 4 stacked LSTM cells ----
    for (int cell = 0; cell < 4; ++cell) {
      const _Float16* WTh; const float* bias; int K;
      if (cell == 0) {
        WTh = WT0h; bias = bc0; K = 384;
        if (tid < 256) inp_s[tid] = qst[tid];
        else if (tid < 384) inp_s[tid] = hcs[0][tid - 256];
      } else {
        WTh = WTRh + (size_t)(cell - 1) * 131072;
        bias = bcR + (cell - 1) * 512; K = 256;
        if (tid < 128) inp_s[tid] = hcs[cell - 1][tid];
        else if (tid < 256) inp_s[tid] = hcs[cell][tid - 128];
      }
      __syncthreads();
      int kper = K >> 4;
      int se = (s_ + g) & 15;           // rotate slice start per block
      int k0 = se * kper;
      const _Float16* wp = WTh + 8 * cg;
      float a[8] = {0.f, 0.f, 0.f, 0.f, 0.f, 0.f, 0.f, 0.f};
      for (int k = k0; k < k0 + kper; k += 8) {
        half8 w0 = *(const half8*)(wp + (size_t)(k + 0) * 512);
        half8 w1 = *(const half8*)(wp + (size_t)(k + 1) * 512);
        half8 w2 = *(const half8*)(wp + (size_t)(k + 2) * 512);
        half8 w3 = *(const half8*)(wp + (size_t)(k + 3) * 512);
        half8 w4 = *(const half8*)(wp + (size_t)(k + 4) * 512);
        half8 w5 = *(const half8*)(wp + (size_t)(k + 5) * 512);
        half8 w6 = *(const half8*)(wp + (size_t)(k + 6) * 512);
        half8 w7 = *(const half8*)(wp + (size_t)(k + 7) * 512);
        float i0 = inp_s[k + 0], i1 = inp_s[k + 1], i2 = inp_s[k + 2], i3 = inp_s[k + 3];
        float i4 = inp_s[k + 4], i5 = inp_s[k + 5], i6 = inp_s[k + 6], i7 = inp_s[k + 7];
#pragma unroll
        for (int j = 0; j < 8; ++j) {
          a[j] += i0 * (float)w0[j] + i1 * (float)w1[j] +
                  i2 * (float)w2[j] + i3 * (float)w3[j];
          a[j] += i4 * (float)w4[j] + i5 * (float)w5[j] +
                  i6 * (float)w6[j] + i7 * (float)w7[j];
        }
      }
#pragma unroll
      for (int j = 0; j < 8; ++j) wpart[s_][8 * cg + j] = a[j];
      __syncthreads();
      if (tid < 512) {
        float acc = bias[tid];
#pragma unroll
        for (int s = 0; s < 16; ++s) acc += wpart[s][tid];
        gates[tid] = acc;
      }
      __syncthreads();
      if (tid < 128) {
        int j = tid;
        float gi = gates[4 * j + 0];
        float gf = gates[4 * j + 1];
        float gc = gates[4 * j + 2];
        float go = gates[4 * j + 3];
        float cp = ccs[cell][j];
        float si = 1.f / (1.f + expf(-gi));
        float sf = 1.f / (1.f + expf(-gf));
        float so = 1.f / (1.f + expf(-go));
        float cn = sf * cp + si * tanhf(gc);
        ccs[cell][j] = cn;
        hcs[cell][j] = so * tanhf(cn);
      }
      __syncthreads();
    }
    // ---- attention, q = new h[3]; x from LDS cache ----
    float* rpart = &wpart[0][0];  // alias: time-disjoint with matvec
    float qx = hcs[3][2 * lane], qy = hcs[3][2 * lane + 1];
    // pass 1: e + max
    float wmax = -3.0e38f;
    for (int n = w16; n < seg; n += 16) {
      float vx, vy;
      if (n < ncache) {
        vx = xs[n * 128 + 2 * lane];
        vy = xs[n * 128 + 2 * lane + 1];
      } else {
        float2 v = x2[(size_t)(s0 + n) * 64 + lane];
        vx = fmaxf(fmaf(v.x, sc0, sh0), 0.f);
        vy = fmaxf(fmaf(v.y, sc1, sh1), 0.f);
      }
      float e = vx * qx + vy * qy;
#pragma unroll
      for (int sh = 32; sh; sh >>= 1) e += __shfl_xor(e, sh);
      if (lane == 0) { if (n < ESC) es[n] = e; else ebuf[s0 + n] = e; }
      wmax = fmaxf(wmax, e);
    }
    if (lane == 0) wred[w16] = wmax;
    __syncthreads();
    if (tid == 0) {
      float m = wred[0];
#pragma unroll
      for (int t = 1; t < 16; ++t) m = fmaxf(m, wred[t]);
      smax_s = m;
    }
    __syncthreads();
    float m = smax_s;
    // pass 2: sum exp
    float loc = 0.f;
    for (int n = tid; n < seg; n += 1024) {
      float e = (n < ESC) ? es[n] : ebuf[s0 + n];
      loc += expf(e - m);
    }
#pragma unroll
    for (int sh = 32; sh; sh >>= 1) loc += __shfl_xor(loc, sh);
    __syncthreads();
    if (lane == 0) wred[w16] = loc;
    __syncthreads();
    if (tid == 0) {
      float s = 0.f;
#pragma unroll
      for (int t = 0; t < 16; ++t) s += wred[t];
      ssum_s = s;
    }
    __syncthreads();
    float inv = 1.0f / ssum_s;
    // pass 3: r = sum a*x
    float rx = 0.f, ry = 0.f;
    for (int n = w16; n < seg; n += 16) {
      float e = (n < ESC) ? es[n] : ebuf[s0 + n];
      float coef = expf(e - m) * inv;
      float vx, vy;
      if (n < ncache) {
        vx = xs[n * 128 + 2 * lane];
        vy = xs[n * 128 + 2 * lane + 1];
      } else {
        float2 v = x2[(size_t)(s0 + n) * 64 + lane];
        vx = fmaxf(fmaf(v.x, sc0, sh0), 0.f);
        vy = fmaxf(fmaf(v.y, sc1, sh1), 0.f);
      }
      rx += coef * vx; ry += coef * vy;
    }
    rpart[w16 * 128 + 2 * lane] = rx;
    rpart[w16 * 128 + 2 * lane + 1] = ry;
    __syncthreads();
    if (tid < 128) {
      float r = 0.f;
#pragma unroll
      for (int t = 0; t < 16; ++t) r += rpart[t * 128 + tid];
      qst[tid] = hcs[3][tid];
      qst[128 + tid] = r;
    }
    __syncthreads();
  }
  // ---- final linear ----
  if (tid < 256) {
    float val = qst[tid];
    float p0 = val * linW[tid];
    float p1 = val * linW[256 + tid];
#pragma unroll
    for (int sh = 32; sh; sh >>= 1) { p0 += __shfl_xor(p0, sh); p1 += __shfl_xor(p1, sh); }
    if (lane == 0) { fred[0][w16] = p0; fred[1][w16] = p1; }
  }
  __syncthreads();
  if (tid == 0) {
    out[2 * g + 0] = fred[0][0] + fred[0][1] + fred[0][2] + fred[0][3] + linb[0];
    out[2 * g + 1] = fred[1][0] + fred[1][1] + fred[1][2] + fred[1][3] + linb[1];
  }
}

// ---------------- launch ----------------

extern "C" void kernel_launch(void* const* d_in, const int* in_sizes, int n_in,
                              void* d_out, int out_size, void* d_ws, size_t ws_size,
                              hipStream_t stream) {
  const float* x = (const float*)d_in[0];
  const int* ei = (const int*)d_in[1];
  const int* batch = (const int*)d_in[2];
  const float* gW[4]  = {(const float*)d_in[3],  (const float*)d_in[7],
                         (const float*)d_in[11], (const float*)d_in[15]};
  const float* gb[4]  = {(const float*)d_in[4],  (const float*)d_in[8],
                         (const float*)d_in[12], (const float*)d_in[16]};
  const float* gga[4] = {(const float*)d_in[5],  (const float*)d_in[9],
                         (const float*)d_in[13], (const float*)d_in[17]};
  const float* gbe[4] = {(const float*)d_in[6],  (const float*)d_in[10],
                         (const float*)d_in[14], (const float*)d_in[18]};
  const float* Wih0 = (const float*)d_in[19];
  const float* Whh0 = (const float*)d_in[20];
  const float* b0   = (const float*)d_in[21];
  const float* WihR = (const float*)d_in[22];
  const float* WhhR = (const float*)d_in[23];
  const float* bR   = (const float*)d_in[24];
  const float* linW = (const float*)d_in[25];
  const float* linb = (const float*)d_in[26];
  float* out = (float*)d_out;

  char* base = (char*)d_ws;
  size_t off = 0;
  auto allocf = [&](size_t n) { float* p = (float*)(base + off); off += n * sizeof(float); return p; };
  float* xa    = allocf(6400000);
  float* xb    = allocf(6400000);
  float* ginWT = allocf(65536);
  _Float16* WT0h = (_Float16*)(base + off); off += 196608 * 2;
  _Float16* WTRh = (_Float16*)(base + off); off += 393216 * 2;
  _Float16* x16a = (_Float16*)(base + off); off += 6400000 * 2;
  _Float16* x16b = (_Float16*)(base + off); off += 6400000 * 2;
  float* bc0   = allocf(512);
  float* bcR   = allocf(1536);
  float* ebuf  = allocf(50000);
  // ---- zero region: stats only (1024 floats = 256 float4) ----
  float* stats = allocf(1024);     // 4 x (sum128|sq128)
  // ---- ints (all fully written before read; no zeroing needed) ----
  int* row_start = (int*)(base + off); off += 50004 * 4;
  int* gptr = (int*)(base + off); off += 260 * 4;
  int* csr = (int*)(base + off); off += 800000 * 4;
  int* packed = (int*)(base + off); off += 800000 * 4;
  int* partial = (int*)(base + off); off += NBIN * NBLK * 4;
  int* block_base = (int*)(base + off); off += NBIN * NBLK * 4;
  int* total = (int*)(base + off); off += 256 * 4;
  int* coarse_base = (int*)(base + off); off += 260 * 4;
  (void)ws_size; (void)in_sizes; (void)n_in; (void)out_size;

  // merged prep: zero | gptr | hist | weight repack | x->fp16  (grid 2961+6250)
  prep_all_kernel<<<9211, 256, 0, stream>>>(batch, ei, gW[0], gW[1], gW[2], gW[3],
                                            Wih0, Whh0, WihR, WhhR, b0, bR, x,
                                            stats, gptr, partial, ginWT, WT0h, WTRh,
                                            bc0, bcR, x16a);
  scan_partials_kernel<<<NBIN, 256, 0, stream>>>(partial, block_base, total);
  scan_totals_kernel<<<1, 256, 0, stream>>>(total, coarse_base);
  bucket_scatter_kernel<<<NBLK, 256, 0, stream>>>(ei, coarse_base, block_base, packed);
  csr_finalize_kernel<<<NBIN, 256, 0, stream>>>(packed, coarse_base, row_start, csr);

  // GIN layer 1 (gather reads fp16 x)
  gin_agg_kernel<false><<<12500, 256, 0, stream>>>(x16a, row_start, csr,
                                                   nullptr, nullptr, nullptr, xb);
  gemm_gin_kernel<false><<<1564, 256, 0, stream>>>(xb, ginWT + 0 * 16384, gb[0],
                                                   nullptr, nullptr, nullptr,
                                                   xa, nullptr, stats + 0, stats + 128, NN);
  // gemm2: only fp16 output needed (sole consumer is gather2)
  gemm_gin_kernel<true><<<1564, 256, 0, stream>>>(xa, ginWT + 1 * 16384, gb[1],
                                                  stats + 0, gga[0], gbe[0],
                                                  nullptr, x16b, stats + 256, stats + 384, NN);
  // GIN layer 2 (BN2 finalize+affine+relu fused into the fp16 gather)
  gin_agg_kernel<true><<<12500, 256, 0, stream>>>(x16b, row_start, csr,
                                                  stats + 256, gga[1], gbe[1], xa);
  gemm_gin_kernel<false><<<1564, 256, 0, stream>>>(xa, ginWT + 2 * 16384, gb[2],
                                                   nullptr, nullptr, nullptr,
                                                   xb, nullptr, stats + 512, stats + 640, NN);
  gemm_gin_kernel<true><<<1564, 256, 0, stream>>>(xb, ginWT + 3 * 16384, gb[3],
                                                  stats + 512, gga[2], gbe[2],
                                                  xa, nullptr, stats + 768, stats + 896, NN);
  // xa holds pre-BN4 features; BN4 fused into set2set x staging

  // fused Set2Set v4 (proven): fp16 weights, 1 graph/block, LDS x-cache
  set2set_kernel<<<256, 1024, 0, stream>>>(xa, gptr, stats + 768, gga[3], gbe[3],
                                           WT0h, WTRh, bc0, bcR, ebuf, linW, linb, out);
}